// Round 2
// baseline (530.066 us; speedup 1.0000x reference)
//
#include <hip/hip_runtime.h>
#include <math.h>

#define NFEAT 128
#define NSPEC 10

// ---------------------------------------------------------------------------
// Sorting (group nodes by species so species-selected GEMMs get B-reuse)
// ---------------------------------------------------------------------------
__global__ void k_hist(const int* __restrict__ species, int* __restrict__ counts, int N) {
    int i = blockIdx.x * blockDim.x + threadIdx.x;
    if (i < N) atomicAdd(&counts[species[i]], 1);
}

__global__ void k_build(const int* __restrict__ counts, int* __restrict__ cursor,
                        int4* __restrict__ table, int* __restrict__ nTiles) {
    if (threadIdx.x == 0 && blockIdx.x == 0) {
        int off = 0, nt = 0;
        for (int s = 0; s < NSPEC; s++) {
            cursor[s] = off;
            int c = counts[s];
            for (int b = 0; b < c; b += 64)
                table[nt++] = make_int4(s, off + b, min(64, c - b), 0);
            off += c;
        }
        nTiles[0] = nt;
    }
}

__global__ void k_scatter(const int* __restrict__ species, int* __restrict__ cursor,
                          int* __restrict__ sorted, int N) {
    int i = blockIdx.x * blockDim.x + threadIdx.x;
    if (i < N) {
        int p = atomicAdd(&cursor[species[i]], 1);
        sorted[p] = i;
    }
}

// ---------------------------------------------------------------------------
// Generic fp32 GEMM: C[64-row tile x 128 cols] = alpha * A(rows,K=128) @ B
// Optional row-gather via (sorted, table) + per-tile species B offset.
// grid.y tiles B cols in chunks of 128 (col offset gy*128, C offset gy*cChunkY).
// ---------------------------------------------------------------------------
__global__ __launch_bounds__(256) void k_gemm(
    const float* __restrict__ A, int aStride,
    const float* __restrict__ B, int bStride, int bSpecStride,
    float* __restrict__ C, int cStride, int cChunkY,
    int M, float alpha,
    const int* __restrict__ sorted,
    const int4* __restrict__ table,
    const int* __restrict__ nTiles)
{
    __shared__ float At[128][64];    // A tile transposed: [k][row]
    __shared__ float Bs[128][128];   // B tile: [k][col]
    const int t = threadIdx.x;
    const int gy = blockIdx.y;

    int start, cnt, spec = 0;
    if (table) {
        if (blockIdx.x >= nTiles[0]) return;
        int4 te = table[blockIdx.x];
        spec = te.x; start = te.y; cnt = te.z;
    } else {
        start = blockIdx.x * 64;
        cnt = M - start;
        if (cnt <= 0) return;
        if (cnt > 64) cnt = 64;
    }

    { // load B tile, coalesced: float4 index idx = t + 256*i over the 128x128 tile
        const float* Bp = B + (long)spec * bSpecStride + (long)gy * 128;
        #pragma unroll
        for (int i = 0; i < 16; i++) {
            int idx = t + 256 * i;           // 0..4095 float4s
            int k = idx >> 5;                // row (32 float4 per row)
            int c = (idx & 31) * 4;          // col in floats
            *(float4*)&Bs[k][c] = *(const float4*)(Bp + (long)k * bStride + c);
        }
    }
    { // load A tile transposed: thread -> row r = t&63, k-chunk of 32
        int r = t & 63;
        int kc = (t >> 6) * 32;
        if (r < cnt) {
            int grow = table ? sorted[start + r] : (start + r);
            const float4* src = (const float4*)(A + (long)grow * aStride + kc);
            #pragma unroll
            for (int i = 0; i < 8; i++) {
                float4 v = src[i];
                At[kc + 4*i + 0][r] = v.x;
                At[kc + 4*i + 1][r] = v.y;
                At[kc + 4*i + 2][r] = v.z;
                At[kc + 4*i + 3][r] = v.w;
            }
        } else {
            #pragma unroll
            for (int i = 0; i < 32; i++) At[kc + i][r] = 0.0f;
        }
    }
    __syncthreads();

    const int c0 = (t & 31) * 4;   // 4 output cols
    const int r0 = (t >> 5) * 8;   // 8 output rows
    float acc[8][4] = {};
    #pragma unroll 8
    for (int k = 0; k < 128; k++) {
        float4 b  = *(const float4*)&Bs[k][c0];
        float4 a0 = *(const float4*)&At[k][r0];
        float4 a1 = *(const float4*)&At[k][r0 + 4];
        float av[8] = {a0.x, a0.y, a0.z, a0.w, a1.x, a1.y, a1.z, a1.w};
        #pragma unroll
        for (int i = 0; i < 8; i++) {
            acc[i][0] += av[i] * b.x;
            acc[i][1] += av[i] * b.y;
            acc[i][2] += av[i] * b.z;
            acc[i][3] += av[i] * b.w;
        }
    }
    #pragma unroll
    for (int i = 0; i < 8; i++) {
        int r = r0 + i;
        if (r < cnt) {
            int grow = table ? sorted[start + r] : (start + r);
            float4 v = make_float4(acc[i][0] * alpha, acc[i][1] * alpha,
                                   acc[i][2] * alpha, acc[i][3] * alpha);
            *(float4*)&C[(long)gy * cChunkY + (long)grow * cStride + c0] = v;
        }
    }
}

// ---------------------------------------------------------------------------
// Fused edge kernel: 64-edge tiles.
//   t1 = silu(ef @ W1 /sqrt8); t2 = silu(t1 @ W2 /8); t3 = silu(t2 @ W3 /8)
//   w0 = t3 @ W4[:, 0:128] / 8;  msgs0[recv] += h[send] * w0 * edge_attrs[e,0]
// ---------------------------------------------------------------------------
__global__ __launch_bounds__(256) void k_edge(
    const float* __restrict__ edge_attrs,   // (E,16)  -- only col 0 used
    const float* __restrict__ edge_feats,   // (E,8)
    const int*   __restrict__ edge_index,   // (2,E)
    const float* __restrict__ W1,           // (8,64)
    const float* __restrict__ W2,           // (64,64)
    const float* __restrict__ W3,           // (64,64)
    const float* __restrict__ W4,           // (64,512) -- cols 0..127 used
    const float* __restrict__ h,            // (N,128), already scaled
    float*       __restrict__ msgs0,        // (N,128), pre-zeroed
    int E)
{
    __shared__ float W1s[8][64];
    __shared__ float W2s[64][64];
    __shared__ float W3s[64][64];
    __shared__ float efT[8][64];
    __shared__ float taT[64][64];   // transposed activations [k][edge]
    __shared__ float tbT[64][64];
    __shared__ int   sendS[64];
    __shared__ int   recvS[64];
    __shared__ float sh0S[64];

    const int t = threadIdx.x;
    // stage MLP weights once per block
    if (t < 128) ((float4*)W1s)[t] = ((const float4*)W1)[t];
    #pragma unroll
    for (int i = 0; i < 4; i++) {
        ((float4*)W2s)[t + 256 * i] = ((const float4*)W2)[t + 256 * i];
        ((float4*)W3s)[t + 256 * i] = ((const float4*)W3)[t + 256 * i];
    }
    __syncthreads();

    const float s1 = 0.3535533905932738f;  // 1/sqrt(8)
    const float s2 = 0.125f;               // 1/sqrt(64)

    const int e0 = (t & 15) * 4;   // 4 edges   (stages t1..t3)
    const int j0 = (t >> 4) * 4;   // 4 hidden units

    int ntiles = (E + 63) >> 6;
    for (int tile = blockIdx.x; tile < ntiles; tile += gridDim.x) {
        int ebase = tile << 6;
        // ---- stage meta + edge feats ----
        if (t < 64) {
            int e = ebase + t;
            if (e < E) {
                sendS[t] = edge_index[e];
                recvS[t] = edge_index[E + e];
                sh0S[t]  = edge_attrs[(long)e * 16];
            } else { sendS[t] = 0; recvS[t] = 0; sh0S[t] = 0.0f; }
        } else if (t < 128) {
            int l = t - 64;
            int e = ebase + l;
            if (e < E) {
                const float4* src = (const float4*)(edge_feats + (long)e * 8);
                float4 v0 = src[0], v1 = src[1];
                efT[0][l] = v0.x; efT[1][l] = v0.y; efT[2][l] = v0.z; efT[3][l] = v0.w;
                efT[4][l] = v1.x; efT[5][l] = v1.y; efT[6][l] = v1.z; efT[7][l] = v1.w;
            } else {
                #pragma unroll
                for (int k = 0; k < 8; k++) efT[k][l] = 0.0f;
            }
        }
        __syncthreads();

        // ---- t1 ----
        {
            float acc[4][4] = {};
            #pragma unroll
            for (int k = 0; k < 8; k++) {
                float4 a = *(const float4*)&efT[k][e0];
                float4 b = *(const float4*)&W1s[k][j0];
                float av[4] = {a.x, a.y, a.z, a.w};
                float bv[4] = {b.x, b.y, b.z, b.w};
                #pragma unroll
                for (int jj = 0; jj < 4; jj++)
                    #pragma unroll
                    for (int ee = 0; ee < 4; ee++)
                        acc[jj][ee] += av[ee] * bv[jj];
            }
            #pragma unroll
            for (int jj = 0; jj < 4; jj++) {
                float4 v;
                float x;
                x = acc[jj][0] * s1; v.x = x / (1.0f + expf(-x));
                x = acc[jj][1] * s1; v.y = x / (1.0f + expf(-x));
                x = acc[jj][2] * s1; v.z = x / (1.0f + expf(-x));
                x = acc[jj][3] * s1; v.w = x / (1.0f + expf(-x));
                *(float4*)&taT[j0 + jj][e0] = v;
            }
        }
        __syncthreads();

        // ---- t2 ----
        {
            float acc[4][4] = {};
            #pragma unroll 4
            for (int k = 0; k < 64; k++) {
                float4 a = *(const float4*)&taT[k][e0];
                float4 b = *(const float4*)&W2s[k][j0];
                float av[4] = {a.x, a.y, a.z, a.w};
                float bv[4] = {b.x, b.y, b.z, b.w};
                #pragma unroll
                for (int jj = 0; jj < 4; jj++)
                    #pragma unroll
                    for (int ee = 0; ee < 4; ee++)
                        acc[jj][ee] += av[ee] * bv[jj];
            }
            #pragma unroll
            for (int jj = 0; jj < 4; jj++) {
                float4 v;
                float x;
                x = acc[jj][0] * s2; v.x = x / (1.0f + expf(-x));
                x = acc[jj][1] * s2; v.y = x / (1.0f + expf(-x));
                x = acc[jj][2] * s2; v.z = x / (1.0f + expf(-x));
                x = acc[jj][3] * s2; v.w = x / (1.0f + expf(-x));
                *(float4*)&tbT[j0 + jj][e0] = v;
            }
        }
        __syncthreads();

        // ---- t3 ----
        {
            float acc[4][4] = {};
            #pragma unroll 4
            for (int k = 0; k < 64; k++) {
                float4 a = *(const float4*)&tbT[k][e0];
                float4 b = *(const float4*)&W3s[k][j0];
                float av[4] = {a.x, a.y, a.z, a.w};
                float bv[4] = {b.x, b.y, b.z, b.w};
                #pragma unroll
                for (int jj = 0; jj < 4; jj++)
                    #pragma unroll
                    for (int ee = 0; ee < 4; ee++)
                        acc[jj][ee] += av[ee] * bv[jj];
            }
            #pragma unroll
            for (int jj = 0; jj < 4; jj++) {
                float4 v;
                float x;
                x = acc[jj][0] * s2; v.x = x / (1.0f + expf(-x));
                x = acc[jj][1] * s2; v.y = x / (1.0f + expf(-x));
                x = acc[jj][2] * s2; v.z = x / (1.0f + expf(-x));
                x = acc[jj][3] * s2; v.w = x / (1.0f + expf(-x));
                *(float4*)&taT[j0 + jj][e0] = v;
            }
        }
        __syncthreads();

        // ---- w0 + gather h[send] + atomic scatter to msgs0[recv] ----
        {
            const int c0  = (t & 31) * 4;   // 4 feature cols
            const int ew0 = (t >> 5) * 8;   // 8 edges
            float acc[8][4] = {};
            #pragma unroll 4
            for (int k = 0; k < 64; k++) {
                float4 b  = *(const float4*)&W4[k * 512 + c0];  // L1/L2-resident
                float4 a0 = *(const float4*)&taT[k][ew0];
                float4 a1 = *(const float4*)&taT[k][ew0 + 4];
                float av[8] = {a0.x, a0.y, a0.z, a0.w, a1.x, a1.y, a1.z, a1.w};
                #pragma unroll
                for (int i = 0; i < 8; i++) {
                    acc[i][0] += av[i] * b.x;
                    acc[i][1] += av[i] * b.y;
                    acc[i][2] += av[i] * b.z;
                    acc[i][3] += av[i] * b.w;
                }
            }
            #pragma unroll
            for (int i = 0; i < 8; i++) {
                int el = ew0 + i;
                int e  = ebase + el;
                if (e < E) {
                    float f = sh0S[el] * s2;         // fold 1/sqrt(H) of w0
                    int snd = sendS[el], rcv = recvS[el];
                    float4 hv = *(const float4*)&h[(long)snd * NFEAT + c0];
                    float* dst = msgs0 + (long)rcv * NFEAT + c0;
                    atomicAdd(dst + 0, acc[i][0] * f * hv.x);
                    atomicAdd(dst + 1, acc[i][1] * f * hv.y);
                    atomicAdd(dst + 2, acc[i][2] * f * hv.z);
                    atomicAdd(dst + 3, acc[i][3] * f * hv.w);
                }
            }
        }
        __syncthreads();   // protect taT/meta before next tile overwrites
    }
}

// ---------------------------------------------------------------------------
extern "C" void kernel_launch(void* const* d_in, const int* in_sizes, int n_in,
                              void* d_out, int out_size, void* d_ws, size_t ws_size,
                              hipStream_t stream) {
    // inputs (setup_inputs order)
    const float* node_feats = (const float*)d_in[1];
    const float* edge_attrs = (const float*)d_in[2];
    const float* edge_feats = (const float*)d_in[3];
    const int*   edge_index = (const int*)  d_in[4];
    const int*   species    = (const int*)  d_in[5];
    const float* Wsn        = (const float*)d_in[6];   // (128,10,128)
    const float* Wup        = (const float*)d_in[7];   // (128,128)
    const float* W1         = (const float*)d_in[8];   // (8,64)
    const float* W2         = (const float*)d_in[9];   // (64,64)
    const float* W3         = (const float*)d_in[10];  // (64,64)
    const float* W4         = (const float*)d_in[11];  // (64,512)
    const float* Wlin       = (const float*)d_in[12];  // (4,128,128) -> l=0
    const float* Wsm        = (const float*)d_in[13];  // (4,128,10,128) -> l=0
    const float* Wout       = (const float*)d_in[14];  // (128,128)

    const int N = in_sizes[5];
    const int E = in_sizes[4] / 2;
    const int NF = NFEAT;

    float* out     = (float*)d_out;
    float* message = out;               // (N,128)
    float* skip    = out + (long)N * NF;

    // workspace carve
    float* ws    = (float*)d_ws;
    float* h     = ws;                        // N*128
    float* msgs0 = h + (long)N * NF;          // N*128
    float* Tst   = msgs0 + (long)N * NF;      // 10*128*128 (stacked W_lin0 @ Wsm0_s)
    float* Comb  = Tst + NSPEC * NF * NF;     // 10*128*128
    int*   sorted = (int*)(Comb + NSPEC * NF * NF);  // N
    int*   counts = sorted + N;               // 16
    int*   cursor = counts + 16;              // 16
    int*   nTiles = cursor + 16;              // 4
    int4*  table  = (int4*)(nTiles + 4);      // up to 256 tiles

    const float aH    = 1.0f / sqrtf((float)NF);                 // h scale
    const float aSkip = 1.0f / sqrtf((float)(NF * NSPEC));       // skip scale
    const float cTot  = 0.25f / ((float)NF * sqrtf((float)(NF * NSPEC))); // c1*c2*c3

    hipMemsetAsync(msgs0, 0, (size_t)N * NF * sizeof(float), stream);
    hipMemsetAsync(counts, 0, 16 * sizeof(int), stream);

    // species grouping
    k_hist   <<<(N + 255) / 256, 256, 0, stream>>>(species, counts, N);
    k_build  <<<1, 64, 0, stream>>>(counts, cursor, table, nTiles);
    k_scatter<<<(N + 255) / 256, 256, 0, stream>>>(species, cursor, sorted, N);

    const int mTiles   = (N + 63) / 64;        // 157
    const int maxTiles = mTiles + NSPEC;       // 167 upper bound on species tiles

    // h = node_feats @ W_up / sqrt(F)
    k_gemm<<<dim3(mTiles, 1), 256, 0, stream>>>(
        node_feats, NF, Wup, NF, 0, h, NF, NF, N, aH, nullptr, nullptr, nullptr);

    // Tst[s][u][w2] = (W_lin0 @ Wsm0[:,s,:])   : A=(128x128), B=(128x1280)
    k_gemm<<<dim3(2, NSPEC), 256, 0, stream>>>(
        Wlin, NF, Wsm, NF * NSPEC, 0, Tst, NF, NF * NF, NF, 1.0f, nullptr, nullptr, nullptr);

    // Comb = Tst(1280x128) @ W_out * cTot
    k_gemm<<<dim3((NSPEC * NF) / 64, 1), 256, 0, stream>>>(
        Tst, NF, Wout, NF, 0, Comb, NF, NF, NSPEC * NF, cTot, nullptr, nullptr, nullptr);

    // skip = gatherGEMM(node_feats, W_skip_node[:,s,:]) / sqrt(F*S)
    k_gemm<<<dim3(maxTiles, 1), 256, 0, stream>>>(
        node_feats, NF, Wsn, NF * NSPEC, NF, skip, NF, NF, N, aSkip, sorted, table, nTiles);

    // fused per-edge MLP + gather + scatter
    int edgeTiles = (E + 63) / 64;
    int edgeGrid  = edgeTiles < 512 ? edgeTiles : 512;
    k_edge<<<edgeGrid, 256, 0, stream>>>(
        edge_attrs, edge_feats, edge_index, W1, W2, W3, W4, h, msgs0, E);

    // message = gatherGEMM(msgs0, Comb[s])
    k_gemm<<<dim3(maxTiles, 1), 256, 0, stream>>>(
        msgs0, NF, Comb, NF, NF * NF, message, NF, NF, N, 1.0f, sorted, table, nTiles);
}

// Round 3
// 421.263 us; speedup vs baseline: 1.2583x; 1.2583x over previous
//
#include <hip/hip_runtime.h>
#include <math.h>

#define NFEAT 128
#define NSPEC 10

// ---------------------------------------------------------------------------
// Species grouping (nodes) — hist / tile-table / scatter
// ---------------------------------------------------------------------------
__global__ void k_hist(const int* __restrict__ species, int* __restrict__ counts, int N) {
    int i = blockIdx.x * blockDim.x + threadIdx.x;
    if (i < N) atomicAdd(&counts[species[i]], 1);
}

__global__ void k_build(const int* __restrict__ counts, int* __restrict__ cursor,
                        int4* __restrict__ table, int* __restrict__ nTiles) {
    if (threadIdx.x == 0 && blockIdx.x == 0) {
        int off = 0, nt = 0;
        for (int s = 0; s < NSPEC; s++) {
            cursor[s] = off;
            int c = counts[s];
            for (int b = 0; b < c; b += 64)
                table[nt++] = make_int4(s, off + b, min(64, c - b), 0);
            off += c;
        }
        nTiles[0] = nt;
    }
}

__global__ void k_scatter(const int* __restrict__ species, int* __restrict__ cursor,
                          int* __restrict__ sorted, int N) {
    int i = blockIdx.x * blockDim.x + threadIdx.x;
    if (i < N) {
        int p = atomicAdd(&cursor[species[i]], 1);
        sorted[p] = i;
    }
}

// ---------------------------------------------------------------------------
// Edge CSR by receiver — hist / single-block scan / scatter
// ---------------------------------------------------------------------------
__global__ void k_ehist(const int* __restrict__ edge_index, int* __restrict__ ehist, int E) {
    int i = blockIdx.x * blockDim.x + threadIdx.x;
    if (i < E) atomicAdd(&ehist[edge_index[E + i]], 1);
}

// single block, 256 threads: exclusive scan of ehist[N] -> estart & ecursor
__global__ void k_escan(const int* __restrict__ ehist, int* __restrict__ estart,
                        int* __restrict__ ecursor, int N) {
    __shared__ int ssum[256];
    const int t = threadIdx.x;
    const int chunk = (N + 255) / 256;
    const int lo = t * chunk;
    const int hi = min(lo + chunk, N);
    int local = 0;
    for (int i = lo; i < hi; i++) local += ehist[i];
    ssum[t] = local;
    __syncthreads();
    // inclusive scan over 256 partial sums
    for (int off = 1; off < 256; off <<= 1) {
        int x = (t >= off) ? ssum[t - off] : 0;
        __syncthreads();
        ssum[t] += x;
        __syncthreads();
    }
    int run = ssum[t] - local;   // exclusive prefix for this thread's chunk
    for (int i = lo; i < hi; i++) {
        estart[i] = run;
        ecursor[i] = run;
        run += ehist[i];
    }
}

__global__ void k_escatter(const int* __restrict__ edge_index, int* __restrict__ ecursor,
                           int* __restrict__ eorder, int E) {
    int i = blockIdx.x * blockDim.x + threadIdx.x;
    if (i < E) {
        int r = edge_index[E + i];
        int p = atomicAdd(&ecursor[r], 1);
        eorder[p] = i;
    }
}

// ---------------------------------------------------------------------------
// Generic fp32 GEMM: C[64-row tile x 128 cols] = alpha * A(rows,K=128) @ B
// Optional row-gather via (sorted, table) + per-tile species B offset.
// ---------------------------------------------------------------------------
__global__ __launch_bounds__(256) void k_gemm(
    const float* __restrict__ A, int aStride,
    const float* __restrict__ B, int bStride, int bSpecStride,
    float* __restrict__ C, int cStride, int cChunkY,
    int M, float alpha,
    const int* __restrict__ sorted,
    const int4* __restrict__ table,
    const int* __restrict__ nTiles)
{
    __shared__ float At[128][64];    // A tile transposed: [k][row]
    __shared__ float Bs[128][128];   // B tile: [k][col]
    const int t = threadIdx.x;
    const int gy = blockIdx.y;

    int start, cnt, spec = 0;
    if (table) {
        if (blockIdx.x >= nTiles[0]) return;
        int4 te = table[blockIdx.x];
        spec = te.x; start = te.y; cnt = te.z;
    } else {
        start = blockIdx.x * 64;
        cnt = M - start;
        if (cnt <= 0) return;
        if (cnt > 64) cnt = 64;
    }

    { // load B tile, coalesced
        const float* Bp = B + (long)spec * bSpecStride + (long)gy * 128;
        #pragma unroll
        for (int i = 0; i < 16; i++) {
            int idx = t + 256 * i;           // 0..4095 float4s
            int k = idx >> 5;                // row (32 float4 per row)
            int c = (idx & 31) * 4;          // col in floats
            *(float4*)&Bs[k][c] = *(const float4*)(Bp + (long)k * bStride + c);
        }
    }
    { // load A tile transposed
        int r = t & 63;
        int kc = (t >> 6) * 32;
        if (r < cnt) {
            int grow = table ? sorted[start + r] : (start + r);
            const float4* src = (const float4*)(A + (long)grow * aStride + kc);
            #pragma unroll
            for (int i = 0; i < 8; i++) {
                float4 v = src[i];
                At[kc + 4*i + 0][r] = v.x;
                At[kc + 4*i + 1][r] = v.y;
                At[kc + 4*i + 2][r] = v.z;
                At[kc + 4*i + 3][r] = v.w;
            }
        } else {
            #pragma unroll
            for (int i = 0; i < 32; i++) At[kc + i][r] = 0.0f;
        }
    }
    __syncthreads();

    const int c0 = (t & 31) * 4;   // 4 output cols
    const int r0 = (t >> 5) * 8;   // 8 output rows
    float acc[8][4] = {};
    #pragma unroll 8
    for (int k = 0; k < 128; k++) {
        float4 b  = *(const float4*)&Bs[k][c0];
        float4 a0 = *(const float4*)&At[k][r0];
        float4 a1 = *(const float4*)&At[k][r0 + 4];
        float av[8] = {a0.x, a0.y, a0.z, a0.w, a1.x, a1.y, a1.z, a1.w};
        #pragma unroll
        for (int i = 0; i < 8; i++) {
            acc[i][0] += av[i] * b.x;
            acc[i][1] += av[i] * b.y;
            acc[i][2] += av[i] * b.z;
            acc[i][3] += av[i] * b.w;
        }
    }
    #pragma unroll
    for (int i = 0; i < 8; i++) {
        int r = r0 + i;
        if (r < cnt) {
            int grow = table ? sorted[start + r] : (start + r);
            float4 v = make_float4(acc[i][0] * alpha, acc[i][1] * alpha,
                                   acc[i][2] * alpha, acc[i][3] * alpha);
            *(float4*)&C[(long)gy * cChunkY + (long)grow * cStride + c0] = v;
        }
    }
}

// ---------------------------------------------------------------------------
// Fused edge kernel, 64-edge tiles.
// MODE 0: original edge order; writes per-edge contribution to wmsg[e][128].
// MODE 1: receiver-sorted order (eorder); run-combined atomics into msgs0.
// ---------------------------------------------------------------------------
template <int MODE>
__global__ __launch_bounds__(256) void k_edge(
    const float* __restrict__ edge_attrs,   // (E,16)  -- only col 0 used
    const float* __restrict__ edge_feats,   // (E,8)
    const int*   __restrict__ edge_index,   // (2,E)
    const int*   __restrict__ eorder,       // (E) sorted edge ids (MODE 1)
    const float* __restrict__ W1,           // (8,64)
    const float* __restrict__ W2,           // (64,64)
    const float* __restrict__ W3,           // (64,64)
    const float* __restrict__ W4,           // (64,512) -- cols 0..127 used
    const float* __restrict__ h,            // (N,128), already scaled
    float*       __restrict__ wmsg,         // (E,128)  (MODE 0)
    float*       __restrict__ msgs0,        // (N,128)  (MODE 1, pre-zeroed)
    int E)
{
    __shared__ float W1s[8][64];
    __shared__ float W2s[64][64];
    __shared__ float W3s[64][64];
    __shared__ float efT[8][64];
    __shared__ float taT[64][64];   // transposed activations [k][edge]
    __shared__ float tbT[64][64];
    __shared__ int   sendS[64];
    __shared__ int   recvS[64];
    __shared__ float sh0S[64];

    const int t = threadIdx.x;
    if (t < 128) ((float4*)W1s)[t] = ((const float4*)W1)[t];
    #pragma unroll
    for (int i = 0; i < 4; i++) {
        ((float4*)W2s)[t + 256 * i] = ((const float4*)W2)[t + 256 * i];
        ((float4*)W3s)[t + 256 * i] = ((const float4*)W3)[t + 256 * i];
    }
    __syncthreads();

    const float s1 = 0.3535533905932738f;  // 1/sqrt(8)
    const float s2 = 0.125f;               // 1/sqrt(64)

    const int e0 = (t & 15) * 4;   // 4 edges   (stages t1..t3)
    const int j0 = (t >> 4) * 4;   // 4 hidden units

    int ntiles = (E + 63) >> 6;
    for (int tile = blockIdx.x; tile < ntiles; tile += gridDim.x) {
        int ebase = tile << 6;
        // ---- stage meta + edge feats ----
        if (t < 64) {
            int p = ebase + t;
            if (p < E) {
                int e = (MODE == 1) ? eorder[p] : p;
                sendS[t] = edge_index[e];
                recvS[t] = edge_index[E + e];
                sh0S[t]  = edge_attrs[(long)e * 16];
            } else { sendS[t] = 0; recvS[t] = -1; sh0S[t] = 0.0f; }
        } else if (t < 128) {
            int l = t - 64;
            int p = ebase + l;
            if (p < E) {
                int e = (MODE == 1) ? eorder[p] : p;
                const float4* src = (const float4*)(edge_feats + (long)e * 8);
                float4 v0 = src[0], v1 = src[1];
                efT[0][l] = v0.x; efT[1][l] = v0.y; efT[2][l] = v0.z; efT[3][l] = v0.w;
                efT[4][l] = v1.x; efT[5][l] = v1.y; efT[6][l] = v1.z; efT[7][l] = v1.w;
            } else {
                #pragma unroll
                for (int k = 0; k < 8; k++) efT[k][l] = 0.0f;
            }
        }
        __syncthreads();

        // ---- t1 ----
        {
            float acc[4][4] = {};
            #pragma unroll
            for (int k = 0; k < 8; k++) {
                float4 a = *(const float4*)&efT[k][e0];
                float4 b = *(const float4*)&W1s[k][j0];
                float av[4] = {a.x, a.y, a.z, a.w};
                float bv[4] = {b.x, b.y, b.z, b.w};
                #pragma unroll
                for (int jj = 0; jj < 4; jj++)
                    #pragma unroll
                    for (int ee = 0; ee < 4; ee++)
                        acc[jj][ee] += av[ee] * bv[jj];
            }
            #pragma unroll
            for (int jj = 0; jj < 4; jj++) {
                float4 v; float x;
                x = acc[jj][0] * s1; v.x = x / (1.0f + expf(-x));
                x = acc[jj][1] * s1; v.y = x / (1.0f + expf(-x));
                x = acc[jj][2] * s1; v.z = x / (1.0f + expf(-x));
                x = acc[jj][3] * s1; v.w = x / (1.0f + expf(-x));
                *(float4*)&taT[j0 + jj][e0] = v;
            }
        }
        __syncthreads();

        // ---- t2 ----
        {
            float acc[4][4] = {};
            #pragma unroll 4
            for (int k = 0; k < 64; k++) {
                float4 a = *(const float4*)&taT[k][e0];
                float4 b = *(const float4*)&W2s[k][j0];
                float av[4] = {a.x, a.y, a.z, a.w};
                float bv[4] = {b.x, b.y, b.z, b.w};
                #pragma unroll
                for (int jj = 0; jj < 4; jj++)
                    #pragma unroll
                    for (int ee = 0; ee < 4; ee++)
                        acc[jj][ee] += av[ee] * bv[jj];
            }
            #pragma unroll
            for (int jj = 0; jj < 4; jj++) {
                float4 v; float x;
                x = acc[jj][0] * s2; v.x = x / (1.0f + expf(-x));
                x = acc[jj][1] * s2; v.y = x / (1.0f + expf(-x));
                x = acc[jj][2] * s2; v.z = x / (1.0f + expf(-x));
                x = acc[jj][3] * s2; v.w = x / (1.0f + expf(-x));
                *(float4*)&tbT[j0 + jj][e0] = v;
            }
        }
        __syncthreads();

        // ---- t3 ----
        {
            float acc[4][4] = {};
            #pragma unroll 4
            for (int k = 0; k < 64; k++) {
                float4 a = *(const float4*)&tbT[k][e0];
                float4 b = *(const float4*)&W3s[k][j0];
                float av[4] = {a.x, a.y, a.z, a.w};
                float bv[4] = {b.x, b.y, b.z, b.w};
                #pragma unroll
                for (int jj = 0; jj < 4; jj++)
                    #pragma unroll
                    for (int ee = 0; ee < 4; ee++)
                        acc[jj][ee] += av[ee] * bv[jj];
            }
            #pragma unroll
            for (int jj = 0; jj < 4; jj++) {
                float4 v; float x;
                x = acc[jj][0] * s2; v.x = x / (1.0f + expf(-x));
                x = acc[jj][1] * s2; v.y = x / (1.0f + expf(-x));
                x = acc[jj][2] * s2; v.z = x / (1.0f + expf(-x));
                x = acc[jj][3] * s2; v.w = x / (1.0f + expf(-x));
                *(float4*)&taT[j0 + jj][e0] = v;
            }
        }
        __syncthreads();

        // ---- w0 + gather h[send] + emit ----
        {
            const int c0  = (t & 31) * 4;   // 4 feature cols
            const int ew0 = (t >> 5) * 8;   // 8 edges
            float acc[8][4] = {};
            #pragma unroll 4
            for (int k = 0; k < 64; k++) {
                float4 b  = *(const float4*)&W4[k * 512 + c0];  // L1/L2-resident
                float4 a0 = *(const float4*)&taT[k][ew0];
                float4 a1 = *(const float4*)&taT[k][ew0 + 4];
                float av[8] = {a0.x, a0.y, a0.z, a0.w, a1.x, a1.y, a1.z, a1.w};
                #pragma unroll
                for (int i = 0; i < 8; i++) {
                    acc[i][0] += av[i] * b.x;
                    acc[i][1] += av[i] * b.y;
                    acc[i][2] += av[i] * b.z;
                    acc[i][3] += av[i] * b.w;
                }
            }
            if (MODE == 0) {
                #pragma unroll
                for (int i = 0; i < 8; i++) {
                    int el = ew0 + i;
                    int e  = ebase + el;
                    if (e < E) {
                        float f = sh0S[el] * s2;
                        int snd = sendS[el];
                        float4 hv = *(const float4*)&h[(long)snd * NFEAT + c0];
                        float4 v = make_float4(acc[i][0] * f * hv.x, acc[i][1] * f * hv.y,
                                               acc[i][2] * f * hv.z, acc[i][3] * f * hv.w);
                        *(float4*)&wmsg[(long)e * NFEAT + c0] = v;
                    }
                }
            } else {
                // run-combine consecutive equal receivers, flush one atomic per run
                float4 sum = make_float4(0.f, 0.f, 0.f, 0.f);
                int cur = recvS[ew0];
                #pragma unroll
                for (int i = 0; i < 8; i++) {
                    int el = ew0 + i;
                    int rcv = recvS[el];
                    float f = sh0S[el] * s2;
                    int snd = sendS[el];
                    float4 hv = *(const float4*)&h[(long)snd * NFEAT + c0];
                    float4 v = make_float4(acc[i][0] * f * hv.x, acc[i][1] * f * hv.y,
                                           acc[i][2] * f * hv.z, acc[i][3] * f * hv.w);
                    if (rcv != cur) {
                        if (cur >= 0) {
                            float* dst = msgs0 + (long)cur * NFEAT + c0;
                            atomicAdd(dst + 0, sum.x); atomicAdd(dst + 1, sum.y);
                            atomicAdd(dst + 2, sum.z); atomicAdd(dst + 3, sum.w);
                        }
                        cur = rcv; sum = v;
                    } else {
                        sum.x += v.x; sum.y += v.y; sum.z += v.z; sum.w += v.w;
                    }
                }
                if (cur >= 0) {
                    float* dst = msgs0 + (long)cur * NFEAT + c0;
                    atomicAdd(dst + 0, sum.x); atomicAdd(dst + 1, sum.y);
                    atomicAdd(dst + 2, sum.z); atomicAdd(dst + 3, sum.w);
                }
            }
        }
        __syncthreads();   // protect shared tiles before next iteration
    }
}

// ---------------------------------------------------------------------------
// CSR gather: one wave per receiver sums its edges' wmsg rows -> msgs0 row.
// ---------------------------------------------------------------------------
__global__ __launch_bounds__(256) void k_gather(
    const float* __restrict__ wmsg, const int* __restrict__ estart,
    const int* __restrict__ ehist, const int* __restrict__ eorder,
    float* __restrict__ msgs0, int N)
{
    int w = (blockIdx.x * blockDim.x + threadIdx.x) >> 6;   // global wave id
    int lane = threadIdx.x & 63;
    int totalWaves = (gridDim.x * blockDim.x) >> 6;
    for (int r = w; r < N; r += totalWaves) {
        int s = estart[r], c = ehist[r];
        float2 sum = make_float2(0.f, 0.f);
        for (int i = 0; i < c; i++) {
            int e = eorder[s + i];
            float2 v = *(const float2*)&wmsg[(long)e * NFEAT + lane * 2];
            sum.x += v.x; sum.y += v.y;
        }
        *(float2*)&msgs0[(long)r * NFEAT + lane * 2] = sum;
    }
}

// ---------------------------------------------------------------------------
extern "C" void kernel_launch(void* const* d_in, const int* in_sizes, int n_in,
                              void* d_out, int out_size, void* d_ws, size_t ws_size,
                              hipStream_t stream) {
    const float* node_feats = (const float*)d_in[1];
    const float* edge_attrs = (const float*)d_in[2];
    const float* edge_feats = (const float*)d_in[3];
    const int*   edge_index = (const int*)  d_in[4];
    const int*   species    = (const int*)  d_in[5];
    const float* Wsn        = (const float*)d_in[6];   // (128,10,128)
    const float* Wup        = (const float*)d_in[7];   // (128,128)
    const float* W1         = (const float*)d_in[8];   // (8,64)
    const float* W2         = (const float*)d_in[9];   // (64,64)
    const float* W3         = (const float*)d_in[10];  // (64,64)
    const float* W4         = (const float*)d_in[11];  // (64,512)
    const float* Wlin       = (const float*)d_in[12];  // (4,128,128) -> l=0
    const float* Wsm        = (const float*)d_in[13];  // (4,128,10,128) -> l=0
    const float* Wout       = (const float*)d_in[14];  // (128,128)

    const int N = in_sizes[5];
    const int E = in_sizes[4] / 2;
    const int NF = NFEAT;

    float* out     = (float*)d_out;
    float* message = out;               // (N,128)
    float* skip    = out + (long)N * NF;

    // workspace carve
    char* wsb = (char*)d_ws;
    size_t off = 0;
    auto carve = [&](size_t bytes) { void* p = wsb + off; off = (off + bytes + 255) & ~(size_t)255; return p; };
    float* h      = (float*)carve((size_t)N * NF * 4);
    float* msgs0  = (float*)carve((size_t)N * NF * 4);
    float* Tst    = (float*)carve((size_t)NSPEC * NF * NF * 4);
    float* Comb   = (float*)carve((size_t)NSPEC * NF * NF * 4);
    int*   sorted = (int*)carve((size_t)N * 4);
    int*   counts = (int*)carve(64);
    int*   cursor = (int*)carve(64);
    int*   nTiles = (int*)carve(16);
    int4*  table  = (int4*)carve(256 * 16);
    int*   ehist  = (int*)carve((size_t)N * 4);
    int*   estart = (int*)carve((size_t)N * 4);
    int*   ecursor= (int*)carve((size_t)N * 4);
    int*   eorder = (int*)carve((size_t)E * 4);
    size_t needB  = off;
    float* wmsg   = (float*)carve((size_t)E * NF * 4);
    size_t needA  = off;
    const bool useA = (ws_size >= needA);
    (void)needB;

    const float aH    = 1.0f / sqrtf((float)NF);
    const float aSkip = 1.0f / sqrtf((float)(NF * NSPEC));
    const float cTot  = 0.25f / ((float)NF * sqrtf((float)(NF * NSPEC)));

    hipMemsetAsync(counts, 0, 64, stream);
    hipMemsetAsync(ehist, 0, (size_t)N * 4, stream);
    if (!useA) hipMemsetAsync(msgs0, 0, (size_t)N * NF * 4, stream);

    // species grouping
    k_hist   <<<(N + 255) / 256, 256, 0, stream>>>(species, counts, N);
    k_build  <<<1, 64, 0, stream>>>(counts, cursor, table, nTiles);
    k_scatter<<<(N + 255) / 256, 256, 0, stream>>>(species, cursor, sorted, N);

    // edge CSR by receiver
    k_ehist   <<<(E + 255) / 256, 256, 0, stream>>>(edge_index, ehist, E);
    k_escan   <<<1, 256, 0, stream>>>(ehist, estart, ecursor, N);
    k_escatter<<<(E + 255) / 256, 256, 0, stream>>>(edge_index, ecursor, eorder, E);

    const int mTiles   = (N + 63) / 64;
    const int maxTiles = mTiles + NSPEC;

    // h = node_feats @ W_up / sqrt(F)
    k_gemm<<<dim3(mTiles, 1), 256, 0, stream>>>(
        node_feats, NF, Wup, NF, 0, h, NF, NF, N, aH, nullptr, nullptr, nullptr);

    // Tst[s] = W_lin0 @ Wsm0[:,s,:]
    k_gemm<<<dim3(2, NSPEC), 256, 0, stream>>>(
        Wlin, NF, Wsm, NF * NSPEC, 0, Tst, NF, NF * NF, NF, 1.0f, nullptr, nullptr, nullptr);

    // Comb = Tst(1280x128) @ W_out * cTot
    k_gemm<<<dim3((NSPEC * NF) / 64, 1), 256, 0, stream>>>(
        Tst, NF, Wout, NF, 0, Comb, NF, NF, NSPEC * NF, cTot, nullptr, nullptr, nullptr);

    // skip = gatherGEMM(node_feats, W_skip_node[:,s,:]) / sqrt(F*S)
    k_gemm<<<dim3(maxTiles, 1), 256, 0, stream>>>(
        node_feats, NF, Wsn, NF * NSPEC, NF, skip, NF, NF, N, aSkip, sorted, table, nTiles);

    // fused per-edge MLP
    int edgeTiles = (E + 63) / 64;
    int edgeGrid  = edgeTiles < 512 ? edgeTiles : 512;
    if (useA) {
        k_edge<0><<<edgeGrid, 256, 0, stream>>>(
            edge_attrs, edge_feats, edge_index, nullptr, W1, W2, W3, W4, h, wmsg, msgs0, E);
        int gBlocks = (N + 3) / 4;       // 4 waves (receivers) per block
        k_gather<<<gBlocks, 256, 0, stream>>>(wmsg, estart, ehist, eorder, msgs0, N);
    } else {
        k_edge<1><<<edgeGrid, 256, 0, stream>>>(
            edge_attrs, edge_feats, edge_index, eorder, W1, W2, W3, W4, h, nullptr, msgs0, E);
    }

    // message = gatherGEMM(msgs0, Comb[s])
    k_gemm<<<dim3(maxTiles, 1), 256, 0, stream>>>(
        msgs0, NF, Comb, NF, NF * NF, message, NF, NF, N, 1.0f, sorted, table, nTiles);
}

// Round 5
// 397.554 us; speedup vs baseline: 1.3333x; 1.0596x over previous
//
#include <hip/hip_runtime.h>
#include <math.h>

#define NFEAT 128
#define NSPEC 10

// ---------------------------------------------------------------------------
// Species grouping (nodes) — hist / tile-table / scatter
// ---------------------------------------------------------------------------
__global__ void k_hist(const int* __restrict__ species, int* __restrict__ counts, int N) {
    int i = blockIdx.x * blockDim.x + threadIdx.x;
    if (i < N) atomicAdd(&counts[species[i]], 1);
}

__global__ void k_build(const int* __restrict__ counts, int* __restrict__ cursor,
                        int4* __restrict__ table, int* __restrict__ nTiles) {
    if (threadIdx.x == 0 && blockIdx.x == 0) {
        int off = 0, nt = 0;
        for (int s = 0; s < NSPEC; s++) {
            cursor[s] = off;
            int c = counts[s];
            for (int b = 0; b < c; b += 64)
                table[nt++] = make_int4(s, off + b, min(64, c - b), 0);
            off += c;
        }
        nTiles[0] = nt;
    }
}

__global__ void k_scatter(const int* __restrict__ species, int* __restrict__ cursor,
                          int* __restrict__ sorted, int N) {
    int i = blockIdx.x * blockDim.x + threadIdx.x;
    if (i < N) {
        int p = atomicAdd(&cursor[species[i]], 1);
        sorted[p] = i;
    }
}

// ---------------------------------------------------------------------------
// Edge sort by receiver — hist / single-block scan / scatter
// ---------------------------------------------------------------------------
__global__ void k_ehist(const int* __restrict__ edge_index, int* __restrict__ ehist, int E) {
    int i = blockIdx.x * blockDim.x + threadIdx.x;
    if (i < E) atomicAdd(&ehist[edge_index[E + i]], 1);
}

// single block, 256 threads: exclusive scan of ehist[N] -> ecursor
__global__ void k_escan(const int* __restrict__ ehist, int* __restrict__ ecursor, int N) {
    __shared__ int ssum[256];
    const int t = threadIdx.x;
    const int chunk = (N + 255) / 256;
    const int lo = t * chunk;
    const int hi = min(lo + chunk, N);
    int local = 0;
    for (int i = lo; i < hi; i++) local += ehist[i];
    ssum[t] = local;
    __syncthreads();
    for (int off = 1; off < 256; off <<= 1) {
        int x = (t >= off) ? ssum[t - off] : 0;
        __syncthreads();
        ssum[t] += x;
        __syncthreads();
    }
    int run = ssum[t] - local;   // exclusive prefix of this thread's chunk
    for (int i = lo; i < hi; i++) {
        ecursor[i] = run;
        run += ehist[i];
    }
}

__global__ void k_escatter(const int* __restrict__ edge_index, int* __restrict__ ecursor,
                           int* __restrict__ eorder, int E) {
    int i = blockIdx.x * blockDim.x + threadIdx.x;
    if (i < E) {
        int r = edge_index[E + i];
        int p = atomicAdd(&ecursor[r], 1);
        eorder[p] = i;
    }
}

// ---------------------------------------------------------------------------
// fp32 GEMM: C[64-row tile x BC cols] = alpha * A(rows,K=128) @ B
// BC=128: full-width B tile (96 KB LDS, for tiny GEMMs).
// BC=64 : half-width B tile (64 KB LDS -> 2 blocks/CU, 2x blocks).
// Optional row-gather via (sorted, table) + per-tile species B offset.
// grid.y: B col offset gy*BC, C offset gy*cChunkY.
// ---------------------------------------------------------------------------
template <int BC>
__global__ __launch_bounds__(256) void k_gemm(
    const float* __restrict__ A, int aStride,
    const float* __restrict__ B, int bStride, int bSpecStride,
    float* __restrict__ C, int cStride, int cChunkY,
    int M, float alpha,
    const int* __restrict__ sorted,
    const int4* __restrict__ table,
    const int* __restrict__ nTiles)
{
    __shared__ float At[128][64];   // A tile transposed: [k][row]
    __shared__ float Bs[128][BC];   // B tile: [k][col]
    const int t = threadIdx.x;
    const int gy = blockIdx.y;

    int start, cnt, spec = 0;
    if (table) {
        if (blockIdx.x >= nTiles[0]) return;
        int4 te = table[blockIdx.x];
        spec = te.x; start = te.y; cnt = te.z;
    } else {
        start = blockIdx.x * 64;
        cnt = M - start;
        if (cnt <= 0) return;
        if (cnt > 64) cnt = 64;
    }

    { // load B tile, coalesced
        const float* Bp = B + (long)spec * bSpecStride + (long)gy * BC;
        constexpr int F4R = BC / 4;          // float4s per row
        #pragma unroll
        for (int i = 0; i < (128 * F4R) / 256; i++) {
            int idx = t + 256 * i;
            int k = idx / F4R;
            int c = (idx % F4R) * 4;
            *(float4*)&Bs[k][c] = *(const float4*)(Bp + (long)k * bStride + c);
        }
    }
    { // load A tile transposed
        int r = t & 63;
        int kc = (t >> 6) * 32;
        if (r < cnt) {
            int grow = table ? sorted[start + r] : (start + r);
            const float4* src = (const float4*)(A + (long)grow * aStride + kc);
            #pragma unroll
            for (int i = 0; i < 8; i++) {
                float4 v = src[i];
                At[kc + 4*i + 0][r] = v.x;
                At[kc + 4*i + 1][r] = v.y;
                At[kc + 4*i + 2][r] = v.z;
                At[kc + 4*i + 3][r] = v.w;
            }
        } else {
            #pragma unroll
            for (int i = 0; i < 32; i++) At[kc + i][r] = 0.0f;
        }
    }
    __syncthreads();

    constexpr int CG   = BC / 4;         // col groups of 4
    constexpr int ROWS = BC / 16;        // rows per thread (8 or 4)
    const int c0 = (t % CG) * 4;
    const int r0 = (t / CG) * ROWS;
    float acc[ROWS][4] = {};
    #pragma unroll 8
    for (int k = 0; k < 128; k++) {
        float4 b = *(const float4*)&Bs[k][c0];
        float av[ROWS];
        #pragma unroll
        for (int i = 0; i < ROWS / 4; i++) {
            float4 a = *(const float4*)&At[k][r0 + 4 * i];
            av[4*i + 0] = a.x; av[4*i + 1] = a.y; av[4*i + 2] = a.z; av[4*i + 3] = a.w;
        }
        #pragma unroll
        for (int i = 0; i < ROWS; i++) {
            acc[i][0] += av[i] * b.x;
            acc[i][1] += av[i] * b.y;
            acc[i][2] += av[i] * b.z;
            acc[i][3] += av[i] * b.w;
        }
    }
    #pragma unroll
    for (int i = 0; i < ROWS; i++) {
        int r = r0 + i;
        if (r < cnt) {
            int grow = table ? sorted[start + r] : (start + r);
            float4 v = make_float4(acc[i][0] * alpha, acc[i][1] * alpha,
                                   acc[i][2] * alpha, acc[i][3] * alpha);
            *(float4*)&C[(long)gy * cChunkY + (long)grow * cStride + c0] = v;
        }
    }
}

// ---------------------------------------------------------------------------
// Fused edge kernel, 64-edge tiles over receiver-sorted edges (eorder).
// MLP t1..t3 + w0, then run-combined atomics into msgs0 (pre-zeroed).
// ---------------------------------------------------------------------------
__global__ __launch_bounds__(256) void k_edge(
    const float* __restrict__ edge_attrs,   // (E,16)  -- only col 0 used
    const float* __restrict__ edge_feats,   // (E,8)
    const int*   __restrict__ edge_index,   // (2,E)
    const int*   __restrict__ eorder,       // (E) receiver-sorted edge ids
    const float* __restrict__ W1,           // (8,64)
    const float* __restrict__ W2,           // (64,64)
    const float* __restrict__ W3,           // (64,64)
    const float* __restrict__ W4,           // (64,512) -- cols 0..127 used
    const float* __restrict__ h,            // (N,128), already scaled
    float*       __restrict__ msgs0,        // (N,128), pre-zeroed
    int E)
{
    __shared__ float W1s[8][64];
    __shared__ float W2s[64][64];
    __shared__ float W3s[64][64];
    __shared__ float efT[8][64];
    __shared__ float taT[64][64];   // transposed activations [k][edge]
    __shared__ float tbT[64][64];
    __shared__ int   sendS[64];
    __shared__ int   recvS[64];
    __shared__ float sh0S[64];

    const int t = threadIdx.x;
    if (t < 128) ((float4*)W1s)[t] = ((const float4*)W1)[t];
    #pragma unroll
    for (int i = 0; i < 4; i++) {
        ((float4*)W2s)[t + 256 * i] = ((const float4*)W2)[t + 256 * i];
        ((float4*)W3s)[t + 256 * i] = ((const float4*)W3)[t + 256 * i];
    }
    __syncthreads();

    const float s1 = 0.3535533905932738f;  // 1/sqrt(8)
    const float s2 = 0.125f;               // 1/sqrt(64)

    const int e0 = (t & 15) * 4;   // 4 edges   (stages t1..t3)
    const int j0 = (t >> 4) * 4;   // 4 hidden units

    int ntiles = (E + 63) >> 6;
    for (int tile = blockIdx.x; tile < ntiles; tile += gridDim.x) {
        int ebase = tile << 6;
        // ---- stage meta + edge feats (gather via eorder) ----
        if (t < 64) {
            int p = ebase + t;
            if (p < E) {
                int e = eorder[p];
                sendS[t] = edge_index[e];
                recvS[t] = edge_index[E + e];
                sh0S[t]  = edge_attrs[(long)e * 16];
            } else { sendS[t] = 0; recvS[t] = -1; sh0S[t] = 0.0f; }
        } else if (t < 128) {
            int l = t - 64;
            int p = ebase + l;
            if (p < E) {
                int e = eorder[p];
                const float4* src = (const float4*)(edge_feats + (long)e * 8);
                float4 v0 = src[0], v1 = src[1];
                efT[0][l] = v0.x; efT[1][l] = v0.y; efT[2][l] = v0.z; efT[3][l] = v0.w;
                efT[4][l] = v1.x; efT[5][l] = v1.y; efT[6][l] = v1.z; efT[7][l] = v1.w;
            } else {
                #pragma unroll
                for (int k = 0; k < 8; k++) efT[k][l] = 0.0f;
            }
        }
        __syncthreads();

        // ---- t1 ----
        {
            float acc[4][4] = {};
            #pragma unroll
            for (int k = 0; k < 8; k++) {
                float4 a = *(const float4*)&efT[k][e0];
                float4 b = *(const float4*)&W1s[k][j0];
                float av[4] = {a.x, a.y, a.z, a.w};
                float bv[4] = {b.x, b.y, b.z, b.w};
                #pragma unroll
                for (int jj = 0; jj < 4; jj++)
                    #pragma unroll
                    for (int ee = 0; ee < 4; ee++)
                        acc[jj][ee] += av[ee] * bv[jj];
            }
            #pragma unroll
            for (int jj = 0; jj < 4; jj++) {
                float4 v; float x;
                x = acc[jj][0] * s1; v.x = x / (1.0f + expf(-x));
                x = acc[jj][1] * s1; v.y = x / (1.0f + expf(-x));
                x = acc[jj][2] * s1; v.z = x / (1.0f + expf(-x));
                x = acc[jj][3] * s1; v.w = x / (1.0f + expf(-x));
                *(float4*)&taT[j0 + jj][e0] = v;
            }
        }
        __syncthreads();

        // ---- t2 ----
        {
            float acc[4][4] = {};
            #pragma unroll 4
            for (int k = 0; k < 64; k++) {
                float4 a = *(const float4*)&taT[k][e0];
                float4 b = *(const float4*)&W2s[k][j0];
                float av[4] = {a.x, a.y, a.z, a.w};
                float bv[4] = {b.x, b.y, b.z, b.w};
                #pragma unroll
                for (int jj = 0; jj < 4; jj++)
                    #pragma unroll
                    for (int ee = 0; ee < 4; ee++)
                        acc[jj][ee] += av[ee] * bv[jj];
            }
            #pragma unroll
            for (int jj = 0; jj < 4; jj++) {
                float4 v; float x;
                x = acc[jj][0] * s2; v.x = x / (1.0f + expf(-x));
                x = acc[jj][1] * s2; v.y = x / (1.0f + expf(-x));
                x = acc[jj][2] * s2; v.z = x / (1.0f + expf(-x));
                x = acc[jj][3] * s2; v.w = x / (1.0f + expf(-x));
                *(float4*)&tbT[j0 + jj][e0] = v;
            }
        }
        __syncthreads();

        // ---- t3 ----
        {
            float acc[4][4] = {};
            #pragma unroll 4
            for (int k = 0; k < 64; k++) {
                float4 a = *(const float4*)&tbT[k][e0];
                float4 b = *(const float4*)&W3s[k][j0];
                float av[4] = {a.x, a.y, a.z, a.w};
                float bv[4] = {b.x, b.y, b.z, b.w};
                #pragma unroll
                for (int jj = 0; jj < 4; jj++)
                    #pragma unroll
                    for (int ee = 0; ee < 4; ee++)
                        acc[jj][ee] += av[ee] * bv[jj];
            }
            #pragma unroll
            for (int jj = 0; jj < 4; jj++) {
                float4 v; float x;
                x = acc[jj][0] * s2; v.x = x / (1.0f + expf(-x));
                x = acc[jj][1] * s2; v.y = x / (1.0f + expf(-x));
                x = acc[jj][2] * s2; v.z = x / (1.0f + expf(-x));
                x = acc[jj][3] * s2; v.w = x / (1.0f + expf(-x));
                *(float4*)&taT[j0 + jj][e0] = v;
            }
        }
        __syncthreads();

        // ---- w0 + gather h[send] + run-combined atomic scatter ----
        {
            const int c0  = (t & 31) * 4;   // 4 feature cols
            const int ew0 = (t >> 5) * 8;   // 8 consecutive sorted edges
            float acc[8][4] = {};
            #pragma unroll 4
            for (int k = 0; k < 64; k++) {
                float4 b  = *(const float4*)&W4[k * 512 + c0];  // L1/L2-resident
                float4 a0 = *(const float4*)&taT[k][ew0];
                float4 a1 = *(const float4*)&taT[k][ew0 + 4];
                float av[8] = {a0.x, a0.y, a0.z, a0.w, a1.x, a1.y, a1.z, a1.w};
                #pragma unroll
                for (int i = 0; i < 8; i++) {
                    acc[i][0] += av[i] * b.x;
                    acc[i][1] += av[i] * b.y;
                    acc[i][2] += av[i] * b.z;
                    acc[i][3] += av[i] * b.w;
                }
            }
            // consecutive sorted edges share receivers -> combine runs, flush once per run
            float4 sum = make_float4(0.f, 0.f, 0.f, 0.f);
            int cur = recvS[ew0];
            #pragma unroll
            for (int i = 0; i < 8; i++) {
                int el = ew0 + i;
                int rcv = recvS[el];
                float f = sh0S[el] * s2;
                int snd = sendS[el];
                float4 hv = *(const float4*)&h[(long)snd * NFEAT + c0];
                float4 v = make_float4(acc[i][0] * f * hv.x, acc[i][1] * f * hv.y,
                                       acc[i][2] * f * hv.z, acc[i][3] * f * hv.w);
                if (rcv != cur) {
                    if (cur >= 0) {
                        float* dst = msgs0 + (long)cur * NFEAT + c0;
                        atomicAdd(dst + 0, sum.x); atomicAdd(dst + 1, sum.y);
                        atomicAdd(dst + 2, sum.z); atomicAdd(dst + 3, sum.w);
                    }
                    cur = rcv; sum = v;
                } else {
                    sum.x += v.x; sum.y += v.y; sum.z += v.z; sum.w += v.w;
                }
            }
            if (cur >= 0) {
                float* dst = msgs0 + (long)cur * NFEAT + c0;
                atomicAdd(dst + 0, sum.x); atomicAdd(dst + 1, sum.y);
                atomicAdd(dst + 2, sum.z); atomicAdd(dst + 3, sum.w);
            }
        }
        __syncthreads();   // protect shared tiles before next iteration
    }
}

// ---------------------------------------------------------------------------
extern "C" void kernel_launch(void* const* d_in, const int* in_sizes, int n_in,
                              void* d_out, int out_size, void* d_ws, size_t ws_size,
                              hipStream_t stream) {
    const float* node_feats = (const float*)d_in[1];
    const float* edge_attrs = (const float*)d_in[2];
    const float* edge_feats = (const float*)d_in[3];
    const int*   edge_index = (const int*)  d_in[4];
    const int*   species    = (const int*)  d_in[5];
    const float* Wsn        = (const float*)d_in[6];   // (128,10,128)
    const float* Wup        = (const float*)d_in[7];   // (128,128)
    const float* W1         = (const float*)d_in[8];   // (8,64)
    const float* W2         = (const float*)d_in[9];   // (64,64)
    const float* W3         = (const float*)d_in[10];  // (64,64)
    const float* W4         = (const float*)d_in[11];  // (64,512)
    const float* Wlin       = (const float*)d_in[12];  // (4,128,128) -> l=0
    const float* Wsm        = (const float*)d_in[13];  // (4,128,10,128) -> l=0
    const float* Wout       = (const float*)d_in[14];  // (128,128)

    const int N = in_sizes[5];
    const int E = in_sizes[4] / 2;
    const int NF = NFEAT;

    float* out     = (float*)d_out;
    float* message = out;               // (N,128)
    float* skip    = out + (long)N * NF;

    // workspace carve (no wmsg buffer needed on the sorted-atomic path)
    char* wsb = (char*)d_ws;
    size_t off = 0;
    auto carve = [&](size_t bytes) { void* p = wsb + off; off = (off + bytes + 255) & ~(size_t)255; return p; };
    float* h      = (float*)carve((size_t)N * NF * 4);
    float* msgs0  = (float*)carve((size_t)N * NF * 4);
    float* Tst    = (float*)carve((size_t)NSPEC * NF * NF * 4);
    float* Comb   = (float*)carve((size_t)NSPEC * NF * NF * 4);
    int*   sorted = (int*)carve((size_t)N * 4);
    int*   counts = (int*)carve(64);
    int*   cursor = (int*)carve(64);
    int*   nTiles = (int*)carve(16);
    int4*  table  = (int4*)carve(256 * 16);
    int*   ehist  = (int*)carve((size_t)N * 4);
    int*   ecursor= (int*)carve((size_t)N * 4);
    int*   eorder = (int*)carve((size_t)E * 4);

    const float aH    = 1.0f / sqrtf((float)NF);
    const float aSkip = 1.0f / sqrtf((float)(NF * NSPEC));
    const float cTot  = 0.25f / ((float)NF * sqrtf((float)(NF * NSPEC)));

    hipMemsetAsync(counts, 0, 64, stream);
    hipMemsetAsync(ehist, 0, (size_t)N * 4, stream);
    hipMemsetAsync(msgs0, 0, (size_t)N * NF * 4, stream);

    // species grouping
    k_hist   <<<(N + 255) / 256, 256, 0, stream>>>(species, counts, N);
    k_build  <<<1, 64, 0, stream>>>(counts, cursor, table, nTiles);
    k_scatter<<<(N + 255) / 256, 256, 0, stream>>>(species, cursor, sorted, N);

    // edge sort by receiver
    k_ehist   <<<(E + 255) / 256, 256, 0, stream>>>(edge_index, ehist, E);
    k_escan   <<<1, 256, 0, stream>>>(ehist, ecursor, N);
    k_escatter<<<(E + 255) / 256, 256, 0, stream>>>(edge_index, ecursor, eorder, E);

    const int mTiles   = (N + 63) / 64;
    const int maxTiles = mTiles + NSPEC;

    // h = node_feats @ W_up / sqrt(F)           (BC=64, 2 col-halves)
    k_gemm<64><<<dim3(mTiles, 2), 256, 0, stream>>>(
        node_feats, NF, Wup, NF, 0, h, NF, 64, N, aH, nullptr, nullptr, nullptr);

    // Tst[s] = W_lin0 @ Wsm0[:,s,:]             (BC=128, gy=species)
    k_gemm<128><<<dim3(2, NSPEC), 256, 0, stream>>>(
        Wlin, NF, Wsm, NF * NSPEC, 0, Tst, NF, NF * NF, NF, 1.0f, nullptr, nullptr, nullptr);

    // Comb = Tst(1280x128) @ W_out * cTot       (BC=128)
    k_gemm<128><<<dim3((NSPEC * NF) / 64, 1), 256, 0, stream>>>(
        Tst, NF, Wout, NF, 0, Comb, NF, NF, NSPEC * NF, cTot, nullptr, nullptr, nullptr);

    // skip = gatherGEMM(node_feats, W_skip_node[:,s,:]) / sqrt(F*S)   (BC=64)
    k_gemm<64><<<dim3(maxTiles, 2), 256, 0, stream>>>(
        node_feats, NF, Wsn, NF * NSPEC, NF, skip, NF, 64, N, aSkip, sorted, table, nTiles);

    // fused per-edge MLP + run-combined atomic scatter (receiver-sorted)
    int edgeTiles = (E + 63) / 64;
    int edgeGrid  = edgeTiles < 512 ? edgeTiles : 512;
    k_edge<<<edgeGrid, 256, 0, stream>>>(
        edge_attrs, edge_feats, edge_index, eorder, W1, W2, W3, W4, h, msgs0, E);

    // message = gatherGEMM(msgs0, Comb[s])      (BC=64)
    k_gemm<64><<<dim3(maxTiles, 2), 256, 0, stream>>>(
        msgs0, NF, Comb, NF, NF * NF, message, NF, 64, N, 1.0f, sorted, table, nTiles);
}

// Round 7
// 363.904 us; speedup vs baseline: 1.4566x; 1.0925x over previous
//
#include <hip/hip_runtime.h>
#include <math.h>

#define NFEAT 128
#define NSPEC 10

// ---------------------------------------------------------------------------
// Fused histograms: node species counts + edge receiver counts
// ---------------------------------------------------------------------------
__global__ void k_histboth(const int* __restrict__ species, const int* __restrict__ edge_index,
                           int* __restrict__ counts, int* __restrict__ ehist, int N, int E) {
    int i = blockIdx.x * blockDim.x + threadIdx.x;
    if (i < N) atomicAdd(&counts[species[i]], 1);
    if (i < E) atomicAdd(&ehist[edge_index[E + i]], 1);
}

// ---------------------------------------------------------------------------
// Species tile table (parallel over one block; serial part = 10 iters)
// ---------------------------------------------------------------------------
__global__ void k_build(const int* __restrict__ counts, int* __restrict__ cursor,
                        int4* __restrict__ table, int* __restrict__ nTiles) {
    __shared__ int off[NSPEC + 1], ts[NSPEC + 1], cnt[NSPEC];
    const int t = threadIdx.x;
    if (t == 0) {
        int o = 0, tt = 0;
        for (int s = 0; s < NSPEC; s++) {
            cnt[s] = counts[s];
            off[s] = o; ts[s] = tt;
            o += cnt[s]; tt += (cnt[s] + 63) >> 6;
        }
        off[NSPEC] = o; ts[NSPEC] = tt;
        nTiles[0] = tt;
    }
    __syncthreads();
    if (t < NSPEC) cursor[t] = off[t];
    int nt = ts[NSPEC];
    for (int i = t; i < nt; i += blockDim.x) {
        int s = 0;
        while (ts[s + 1] <= i) s++;
        int b = i - ts[s];
        table[i] = make_int4(s, off[s] + b * 64, min(64, cnt[s] - b * 64), 0);
    }
}

__global__ void k_scatter(const int* __restrict__ species, int* __restrict__ cursor,
                          int* __restrict__ sorted, int N) {
    int i = blockIdx.x * blockDim.x + threadIdx.x;
    if (i < N) {
        int p = atomicAdd(&cursor[species[i]], 1);
        sorted[p] = i;
    }
}

// single block, 256 threads: exclusive scan of ehist[N] -> ecursor
__global__ void k_escan(const int* __restrict__ ehist, int* __restrict__ ecursor, int N) {
    __shared__ int ssum[256];
    const int t = threadIdx.x;
    const int chunk = (N + 255) / 256;
    const int lo = t * chunk;
    const int hi = min(lo + chunk, N);
    int local = 0;
    for (int i = lo; i < hi; i++) local += ehist[i];
    ssum[t] = local;
    __syncthreads();
    for (int off = 1; off < 256; off <<= 1) {
        int x = (t >= off) ? ssum[t - off] : 0;
        __syncthreads();
        ssum[t] += x;
        __syncthreads();
    }
    int run = ssum[t] - local;
    for (int i = lo; i < hi; i++) {
        ecursor[i] = run;
        run += ehist[i];
    }
}

// ---------------------------------------------------------------------------
// Edge gather into receiver-sorted order: payload moved, not just index.
// Reads coalesced (edge i), writes scattered once. k_edge then streams.
// ---------------------------------------------------------------------------
__global__ void k_egather(const int* __restrict__ edge_index, const float* __restrict__ edge_attrs,
                          const float* __restrict__ edge_feats, int* __restrict__ ecursor,
                          int* __restrict__ sendG, int* __restrict__ recvG,
                          float* __restrict__ sh0G, float* __restrict__ efG, int E) {
    int i = blockIdx.x * blockDim.x + threadIdx.x;
    if (i < E) {
        int r = edge_index[E + i];
        int p = atomicAdd(&ecursor[r], 1);
        sendG[p] = edge_index[i];
        recvG[p] = r;
        sh0G[p]  = edge_attrs[(long)i * 16];
        float4 v0 = *(const float4*)(edge_feats + (long)i * 8);
        float4 v1 = *(const float4*)(edge_feats + (long)i * 8 + 4);
        *(float4*)(efG + (long)p * 8)     = v0;
        *(float4*)(efG + (long)p * 8 + 4) = v1;
    }
}

// ---------------------------------------------------------------------------
// fp32 GEMM: C[64-row tile x BC cols] = alpha * A(rows,K=128) @ B
// BC=128: full-width B tile (96 KB LDS). BC=64: 64 KB LDS -> 2 blocks/CU.
// Optional row-gather via (sorted, table) + per-tile species B offset.
// ---------------------------------------------------------------------------
template <int BC>
__global__ __launch_bounds__(256) void k_gemm(
    const float* __restrict__ A, int aStride,
    const float* __restrict__ B, int bStride, int bSpecStride,
    float* __restrict__ C, int cStride, int cChunkY,
    int M, float alpha,
    const int* __restrict__ sorted,
    const int4* __restrict__ table,
    const int* __restrict__ nTiles)
{
    __shared__ float At[128][64];
    __shared__ float Bs[128][BC];
    const int t = threadIdx.x;
    const int gy = blockIdx.y;

    int start, cnt, spec = 0;
    if (table) {
        if (blockIdx.x >= nTiles[0]) return;
        int4 te = table[blockIdx.x];
        spec = te.x; start = te.y; cnt = te.z;
    } else {
        start = blockIdx.x * 64;
        cnt = M - start;
        if (cnt <= 0) return;
        if (cnt > 64) cnt = 64;
    }

    {
        const float* Bp = B + (long)spec * bSpecStride + (long)gy * BC;
        constexpr int F4R = BC / 4;
        #pragma unroll
        for (int i = 0; i < (128 * F4R) / 256; i++) {
            int idx = t + 256 * i;
            int k = idx / F4R;
            int c = (idx % F4R) * 4;
            *(float4*)&Bs[k][c] = *(const float4*)(Bp + (long)k * bStride + c);
        }
    }
    {
        int r = t & 63;
        int kc = (t >> 6) * 32;
        if (r < cnt) {
            int grow = table ? sorted[start + r] : (start + r);
            const float4* src = (const float4*)(A + (long)grow * aStride + kc);
            #pragma unroll
            for (int i = 0; i < 8; i++) {
                float4 v = src[i];
                At[kc + 4*i + 0][r] = v.x;
                At[kc + 4*i + 1][r] = v.y;
                At[kc + 4*i + 2][r] = v.z;
                At[kc + 4*i + 3][r] = v.w;
            }
        } else {
            #pragma unroll
            for (int i = 0; i < 32; i++) At[kc + i][r] = 0.0f;
        }
    }
    __syncthreads();

    constexpr int CG   = BC / 4;
    constexpr int ROWS = BC / 16;
    const int c0 = (t % CG) * 4;
    const int r0 = (t / CG) * ROWS;
    float acc[ROWS][4] = {};
    #pragma unroll 8
    for (int k = 0; k < 128; k++) {
        float4 b = *(const float4*)&Bs[k][c0];
        float av[ROWS];
        #pragma unroll
        for (int i = 0; i < ROWS / 4; i++) {
            float4 a = *(const float4*)&At[k][r0 + 4 * i];
            av[4*i + 0] = a.x; av[4*i + 1] = a.y; av[4*i + 2] = a.z; av[4*i + 3] = a.w;
        }
        #pragma unroll
        for (int i = 0; i < ROWS; i++) {
            acc[i][0] += av[i] * b.x;
            acc[i][1] += av[i] * b.y;
            acc[i][2] += av[i] * b.z;
            acc[i][3] += av[i] * b.w;
        }
    }
    #pragma unroll
    for (int i = 0; i < ROWS; i++) {
        int r = r0 + i;
        if (r < cnt) {
            int grow = table ? sorted[start + r] : (start + r);
            float4 v = make_float4(acc[i][0] * alpha, acc[i][1] * alpha,
                                   acc[i][2] * alpha, acc[i][3] * alpha);
            *(float4*)&C[(long)gy * cChunkY + (long)grow * cStride + c0] = v;
        }
    }
}

// ---------------------------------------------------------------------------
// Fused edge kernel v2: 64-edge tiles over PRE-GATHERED receiver-sorted data.
// LDS = W1(2K)+W2(16K)+act(16K)+efT(2K)+meta(0.8K) ~= 37 KB -> 4 blocks/CU.
// act is updated in place (read->bar->write->bar). W3/W4 read via L1.
// ---------------------------------------------------------------------------
__global__ __launch_bounds__(256) void k_edge(
    const int*   __restrict__ sendG,    // (E) sorted
    const int*   __restrict__ recvG,    // (E) sorted
    const float* __restrict__ sh0G,     // (E) sorted
    const float* __restrict__ efG,      // (E,8) sorted
    const float* __restrict__ W1,       // (8,64)
    const float* __restrict__ W2,       // (64,64)
    const float* __restrict__ W3,       // (64,64)  via L1
    const float* __restrict__ W4,       // (64,512) cols 0..127 via L1
    const float* __restrict__ h,        // (N,128) scaled
    float*       __restrict__ msgs0,    // (N,128) pre-zeroed
    int E)
{
    __shared__ float W1s[8][64];
    __shared__ float W2s[64][64];
    __shared__ float act[64][64];       // [hidden][edge], in-place across stages
    __shared__ float efT[8][64];
    __shared__ int   sendS[64];
    __shared__ int   recvS[64];
    __shared__ float sh0S[64];

    const int t = threadIdx.x;
    if (t < 128) ((float4*)W1s)[t] = ((const float4*)W1)[t];
    #pragma unroll
    for (int i = 0; i < 4; i++)
        ((float4*)W2s)[t + 256 * i] = ((const float4*)W2)[t + 256 * i];
    __syncthreads();

    const float s1 = 0.3535533905932738f;  // 1/sqrt(8)
    const float s2 = 0.125f;               // 1/sqrt(64)

    const int e0 = (t & 15) * 4;   // 4 edges   (stages t1..t3)
    const int j0 = (t >> 4) * 4;   // 4 hidden units

    int ntiles = (E + 63) >> 6;
    for (int tile = blockIdx.x; tile < ntiles; tile += gridDim.x) {
        int ebase = tile << 6;
        // ---- stage meta + edge feats (all coalesced; data pre-sorted) ----
        if (t < 64) {
            int p = ebase + t;
            if (p < E) {
                sendS[t] = sendG[p];
                recvS[t] = recvG[p];
                sh0S[t]  = sh0G[p];
            } else { sendS[t] = 0; recvS[t] = -1; sh0S[t] = 0.0f; }
        } else if (t < 128) {
            int l = t - 64;
            int p = ebase + l;
            if (p < E) {
                float4 v0 = *(const float4*)(efG + (long)p * 8);
                float4 v1 = *(const float4*)(efG + (long)p * 8 + 4);
                efT[0][l] = v0.x; efT[1][l] = v0.y; efT[2][l] = v0.z; efT[3][l] = v0.w;
                efT[4][l] = v1.x; efT[5][l] = v1.y; efT[6][l] = v1.z; efT[7][l] = v1.w;
            } else {
                #pragma unroll
                for (int k = 0; k < 8; k++) efT[k][l] = 0.0f;
            }
        }
        __syncthreads();                                   // B1

        // ---- t1: read efT -> write act ----
        {
            float acc[4][4] = {};
            #pragma unroll
            for (int k = 0; k < 8; k++) {
                float4 a = *(const float4*)&efT[k][e0];
                float4 b = *(const float4*)&W1s[k][j0];
                float av[4] = {a.x, a.y, a.z, a.w};
                float bv[4] = {b.x, b.y, b.z, b.w};
                #pragma unroll
                for (int jj = 0; jj < 4; jj++)
                    #pragma unroll
                    for (int ee = 0; ee < 4; ee++)
                        acc[jj][ee] += av[ee] * bv[jj];
            }
            #pragma unroll
            for (int jj = 0; jj < 4; jj++) {
                float4 v; float x;
                x = acc[jj][0] * s1; v.x = x / (1.0f + __expf(-x));
                x = acc[jj][1] * s1; v.y = x / (1.0f + __expf(-x));
                x = acc[jj][2] * s1; v.z = x / (1.0f + __expf(-x));
                x = acc[jj][3] * s1; v.w = x / (1.0f + __expf(-x));
                *(float4*)&act[j0 + jj][e0] = v;
            }
        }
        __syncthreads();                                   // B2

        // ---- t2: read act + W2s -> acc; write back in place ----
        {
            float acc[4][4] = {};
            #pragma unroll 4
            for (int k = 0; k < 64; k++) {
                float4 a = *(const float4*)&act[k][e0];
                float4 b = *(const float4*)&W2s[k][j0];
                float av[4] = {a.x, a.y, a.z, a.w};
                float bv[4] = {b.x, b.y, b.z, b.w};
                #pragma unroll
                for (int jj = 0; jj < 4; jj++)
                    #pragma unroll
                    for (int ee = 0; ee < 4; ee++)
                        acc[jj][ee] += av[ee] * bv[jj];
            }
            __syncthreads();                               // B3: all reads done
            #pragma unroll
            for (int jj = 0; jj < 4; jj++) {
                float4 v; float x;
                x = acc[jj][0] * s2; v.x = x / (1.0f + __expf(-x));
                x = acc[jj][1] * s2; v.y = x / (1.0f + __expf(-x));
                x = acc[jj][2] * s2; v.z = x / (1.0f + __expf(-x));
                x = acc[jj][3] * s2; v.w = x / (1.0f + __expf(-x));
                *(float4*)&act[j0 + jj][e0] = v;
            }
        }
        __syncthreads();                                   // B4

        // ---- t3: read act + W3 (global, L1-hot) -> acc; write back ----
        {
            float acc[4][4] = {};
            #pragma unroll 4
            for (int k = 0; k < 64; k++) {
                float4 a = *(const float4*)&act[k][e0];
                float4 b = *(const float4*)(W3 + k * 64 + j0);
                float av[4] = {a.x, a.y, a.z, a.w};
                float bv[4] = {b.x, b.y, b.z, b.w};
                #pragma unroll
                for (int jj = 0; jj < 4; jj++)
                    #pragma unroll
                    for (int ee = 0; ee < 4; ee++)
                        acc[jj][ee] += av[ee] * bv[jj];
            }
            __syncthreads();                               // B5: all reads done
            #pragma unroll
            for (int jj = 0; jj < 4; jj++) {
                float4 v; float x;
                x = acc[jj][0] * s2; v.x = x / (1.0f + __expf(-x));
                x = acc[jj][1] * s2; v.y = x / (1.0f + __expf(-x));
                x = acc[jj][2] * s2; v.z = x / (1.0f + __expf(-x));
                x = acc[jj][3] * s2; v.w = x / (1.0f + __expf(-x));
                *(float4*)&act[j0 + jj][e0] = v;
            }
        }
        __syncthreads();                                   // B6

        // ---- w0 + gather h[send] + run-combined atomic scatter ----
        {
            const int c0  = (t & 31) * 4;   // 4 feature cols
            const int ew0 = (t >> 5) * 8;   // 8 consecutive sorted edges
            float acc[8][4] = {};
            #pragma unroll 4
            for (int k = 0; k < 64; k++) {
                float4 b  = *(const float4*)&W4[k * 512 + c0];
                float4 a0 = *(const float4*)&act[k][ew0];
                float4 a1 = *(const float4*)&act[k][ew0 + 4];
                float av[8] = {a0.x, a0.y, a0.z, a0.w, a1.x, a1.y, a1.z, a1.w};
                #pragma unroll
                for (int i = 0; i < 8; i++) {
                    acc[i][0] += av[i] * b.x;
                    acc[i][1] += av[i] * b.y;
                    acc[i][2] += av[i] * b.z;
                    acc[i][3] += av[i] * b.w;
                }
            }
            float4 sum = make_float4(0.f, 0.f, 0.f, 0.f);
            int cur = recvS[ew0];
            #pragma unroll
            for (int i = 0; i < 8; i++) {
                int el = ew0 + i;
                int rcv = recvS[el];
                float f = sh0S[el] * s2;
                int snd = sendS[el];
                float4 hv = *(const float4*)&h[(long)snd * NFEAT + c0];
                float4 v = make_float4(acc[i][0] * f * hv.x, acc[i][1] * f * hv.y,
                                       acc[i][2] * f * hv.z, acc[i][3] * f * hv.w);
                if (rcv != cur) {
                    if (cur >= 0) {
                        float* dst = msgs0 + (long)cur * NFEAT + c0;
                        atomicAdd(dst + 0, sum.x); atomicAdd(dst + 1, sum.y);
                        atomicAdd(dst + 2, sum.z); atomicAdd(dst + 3, sum.w);
                    }
                    cur = rcv; sum = v;
                } else {
                    sum.x += v.x; sum.y += v.y; sum.z += v.z; sum.w += v.w;
                }
            }
            if (cur >= 0) {
                float* dst = msgs0 + (long)cur * NFEAT + c0;
                atomicAdd(dst + 0, sum.x); atomicAdd(dst + 1, sum.y);
                atomicAdd(dst + 2, sum.z); atomicAdd(dst + 3, sum.w);
            }
        }
        __syncthreads();                                   // B7: protect act/meta
    }
}

// ---------------------------------------------------------------------------
extern "C" void kernel_launch(void* const* d_in, const int* in_sizes, int n_in,
                              void* d_out, int out_size, void* d_ws, size_t ws_size,
                              hipStream_t stream) {
    const float* node_feats = (const float*)d_in[1];
    const float* edge_attrs = (const float*)d_in[2];
    const float* edge_feats = (const float*)d_in[3];
    const int*   edge_index = (const int*)  d_in[4];
    const int*   species    = (const int*)  d_in[5];
    const float* Wsn        = (const float*)d_in[6];   // (128,10,128)
    const float* Wup        = (const float*)d_in[7];   // (128,128)
    const float* W1         = (const float*)d_in[8];   // (8,64)
    const float* W2         = (const float*)d_in[9];   // (64,64)
    const float* W3         = (const float*)d_in[10];  // (64,64)
    const float* W4         = (const float*)d_in[11];  // (64,512)
    const float* Wlin       = (const float*)d_in[12];  // (4,128,128) -> l=0
    const float* Wsm        = (const float*)d_in[13];  // (4,128,10,128) -> l=0
    const float* Wout       = (const float*)d_in[14];  // (128,128)

    const int N = in_sizes[5];
    const int E = in_sizes[4] / 2;
    const int NF = NFEAT;

    float* out     = (float*)d_out;
    float* message = out;               // (N,128)
    float* skip    = out + (long)N * NF;

    // workspace carve
    char* wsb = (char*)d_ws;
    size_t off = 0;
    auto carve = [&](size_t bytes) { void* p = wsb + off; off = (off + bytes + 255) & ~(size_t)255; return p; };
    float* h      = (float*)carve((size_t)N * NF * 4);
    float* msgs0  = (float*)carve((size_t)N * NF * 4);
    float* Tst    = (float*)carve((size_t)NSPEC * NF * NF * 4);
    float* Comb   = (float*)carve((size_t)NSPEC * NF * NF * 4);
    int*   sorted = (int*)carve((size_t)N * 4);
    int*   counts = (int*)carve(64);
    int*   cursor = (int*)carve(64);
    int*   nTiles = (int*)carve(16);
    int4*  table  = (int4*)carve(256 * 16);
    int*   ehist  = (int*)carve((size_t)N * 4);
    int*   ecursor= (int*)carve((size_t)N * 4);
    int*   sendG  = (int*)carve((size_t)E * 4);
    int*   recvG  = (int*)carve((size_t)E * 4);
    float* sh0G   = (float*)carve((size_t)E * 4);
    float* efG    = (float*)carve((size_t)E * 8 * 4);

    const float aH    = 1.0f / sqrtf((float)NF);
    const float aSkip = 1.0f / sqrtf((float)(NF * NSPEC));
    const float cTot  = 0.25f / ((float)NF * sqrtf((float)(NF * NSPEC)));

    hipMemsetAsync(counts, 0, 64, stream);
    hipMemsetAsync(ehist, 0, (size_t)N * 4, stream);
    hipMemsetAsync(msgs0, 0, (size_t)N * NF * 4, stream);

    // histograms (nodes by species, edges by receiver)
    k_histboth<<<(max(N, E) + 255) / 256, 256, 0, stream>>>(species, edge_index, counts, ehist, N, E);
    // species tile table + node scatter
    k_build  <<<1, 256, 0, stream>>>(counts, cursor, table, nTiles);
    k_scatter<<<(N + 255) / 256, 256, 0, stream>>>(species, cursor, sorted, N);
    // edge scan + payload gather into sorted order
    k_escan  <<<1, 256, 0, stream>>>(ehist, ecursor, N);
    k_egather<<<(E + 255) / 256, 256, 0, stream>>>(edge_index, edge_attrs, edge_feats,
                                                   ecursor, sendG, recvG, sh0G, efG, E);

    const int mTiles   = (N + 63) / 64;
    const int maxTiles = mTiles + NSPEC;

    // h = node_feats @ W_up / sqrt(F)           (BC=64, 2 col-halves)
    k_gemm<64><<<dim3(mTiles, 2), 256, 0, stream>>>(
        node_feats, NF, Wup, NF, 0, h, NF, 64, N, aH, nullptr, nullptr, nullptr);

    // Tst[s] = W_lin0 @ Wsm0[:,s,:]             (BC=128, gy=species)
    k_gemm<128><<<dim3(2, NSPEC), 256, 0, stream>>>(
        Wlin, NF, Wsm, NF * NSPEC, 0, Tst, NF, NF * NF, NF, 1.0f, nullptr, nullptr, nullptr);

    // Comb = Tst(1280x128) @ W_out * cTot       (BC=128)
    k_gemm<128><<<dim3((NSPEC * NF) / 64, 1), 256, 0, stream>>>(
        Tst, NF, Wout, NF, 0, Comb, NF, NF, NSPEC * NF, cTot, nullptr, nullptr, nullptr);

    // skip = gatherGEMM(node_feats, W_skip_node[:,s,:]) / sqrt(F*S)   (BC=64)
    k_gemm<64><<<dim3(maxTiles, 2), 256, 0, stream>>>(
        node_feats, NF, Wsn, NF * NSPEC, NF, skip, NF, 64, N, aSkip, sorted, table, nTiles);

    // fused per-edge MLP + run-combined atomic scatter (pre-sorted data)
    int edgeTiles = (E + 63) / 64;
    int edgeGrid  = edgeTiles < 1024 ? edgeTiles : 1024;   // 4 blocks/CU
    k_edge<<<edgeGrid, 256, 0, stream>>>(
        sendG, recvG, sh0G, efG, W1, W2, W3, W4, h, msgs0, E);

    // message = gatherGEMM(msgs0, Comb[s])      (BC=64)
    k_gemm<64><<<dim3(maxTiles, 2), 256, 0, stream>>>(
        msgs0, NF, Comb, NF, NF * NF, message, NF, 64, N, 1.0f, sorted, table, nTiles);
}

// Round 8
// 362.856 us; speedup vs baseline: 1.4608x; 1.0029x over previous
//
#include <hip/hip_runtime.h>
#include <math.h>

#define NFEAT 128
#define NSPEC 10

// ---------------------------------------------------------------------------
// Fused histograms: node species counts + edge receiver counts
// ---------------------------------------------------------------------------
__global__ void k_histboth(const int* __restrict__ species, const int* __restrict__ edge_index,
                           int* __restrict__ counts, int* __restrict__ ehist, int N, int E) {
    int i = blockIdx.x * blockDim.x + threadIdx.x;
    if (i < N) atomicAdd(&counts[species[i]], 1);
    if (i < E) atomicAdd(&ehist[edge_index[E + i]], 1);
}

// ---------------------------------------------------------------------------
// Species tile table (one block; serial part = 10 iters)
// ---------------------------------------------------------------------------
__global__ void k_build(const int* __restrict__ counts, int* __restrict__ cursor,
                        int4* __restrict__ table, int* __restrict__ nTiles) {
    __shared__ int off[NSPEC + 1], ts[NSPEC + 1], cnt[NSPEC];
    const int t = threadIdx.x;
    if (t == 0) {
        int o = 0, tt = 0;
        for (int s = 0; s < NSPEC; s++) {
            cnt[s] = counts[s];
            off[s] = o; ts[s] = tt;
            o += cnt[s]; tt += (cnt[s] + 63) >> 6;
        }
        off[NSPEC] = o; ts[NSPEC] = tt;
        nTiles[0] = tt;
    }
    __syncthreads();
    if (t < NSPEC) cursor[t] = off[t];
    int nt = ts[NSPEC];
    for (int i = t; i < nt; i += blockDim.x) {
        int s = 0;
        while (ts[s + 1] <= i) s++;
        int b = i - ts[s];
        table[i] = make_int4(s, off[s] + b * 64, min(64, cnt[s] - b * 64), 0);
    }
}

__global__ void k_scatter(const int* __restrict__ species, int* __restrict__ cursor,
                          int* __restrict__ sorted, int N) {
    int i = blockIdx.x * blockDim.x + threadIdx.x;
    if (i < N) {
        int p = atomicAdd(&cursor[species[i]], 1);
        sorted[p] = i;
    }
}

// single block, 256 threads: exclusive scan of ehist[N] -> ecursor
__global__ void k_escan(const int* __restrict__ ehist, int* __restrict__ ecursor, int N) {
    __shared__ int ssum[256];
    const int t = threadIdx.x;
    const int chunk = (N + 255) / 256;
    const int lo = t * chunk;
    const int hi = min(lo + chunk, N);
    int local = 0;
    for (int i = lo; i < hi; i++) local += ehist[i];
    ssum[t] = local;
    __syncthreads();
    for (int off = 1; off < 256; off <<= 1) {
        int x = (t >= off) ? ssum[t - off] : 0;
        __syncthreads();
        ssum[t] += x;
        __syncthreads();
    }
    int run = ssum[t] - local;
    for (int i = lo; i < hi; i++) {
        ecursor[i] = run;
        run += ehist[i];
    }
}

// ---------------------------------------------------------------------------
// Edge gather into receiver-sorted order (payload moved once, streamed later)
// ---------------------------------------------------------------------------
__global__ void k_egather(const int* __restrict__ edge_index, const float* __restrict__ edge_attrs,
                          const float* __restrict__ edge_feats, int* __restrict__ ecursor,
                          int* __restrict__ sendG, int* __restrict__ recvG,
                          float* __restrict__ sh0G, float* __restrict__ efG, int E) {
    int i = blockIdx.x * blockDim.x + threadIdx.x;
    if (i < E) {
        int r = edge_index[E + i];
        int p = atomicAdd(&ecursor[r], 1);
        sendG[p] = edge_index[i];
        recvG[p] = r;
        sh0G[p]  = edge_attrs[(long)i * 16];
        float4 v0 = *(const float4*)(edge_feats + (long)i * 8);
        float4 v1 = *(const float4*)(edge_feats + (long)i * 8 + 4);
        *(float4*)(efG + (long)p * 8)     = v0;
        *(float4*)(efG + (long)p * 8 + 4) = v1;
    }
}

// ---------------------------------------------------------------------------
// fp32 GEMM (unchanged): C[64-row tile x BC cols] = alpha * A @ B
// ---------------------------------------------------------------------------
template <int BC>
__global__ __launch_bounds__(256) void k_gemm(
    const float* __restrict__ A, int aStride,
    const float* __restrict__ B, int bStride, int bSpecStride,
    float* __restrict__ C, int cStride, int cChunkY,
    int M, float alpha,
    const int* __restrict__ sorted,
    const int4* __restrict__ table,
    const int* __restrict__ nTiles)
{
    __shared__ float At[128][64];
    __shared__ float Bs[128][BC];
    const int t = threadIdx.x;
    const int gy = blockIdx.y;

    int start, cnt, spec = 0;
    if (table) {
        if (blockIdx.x >= nTiles[0]) return;
        int4 te = table[blockIdx.x];
        spec = te.x; start = te.y; cnt = te.z;
    } else {
        start = blockIdx.x * 64;
        cnt = M - start;
        if (cnt <= 0) return;
        if (cnt > 64) cnt = 64;
    }

    {
        const float* Bp = B + (long)spec * bSpecStride + (long)gy * BC;
        constexpr int F4R = BC / 4;
        #pragma unroll
        for (int i = 0; i < (128 * F4R) / 256; i++) {
            int idx = t + 256 * i;
            int k = idx / F4R;
            int c = (idx % F4R) * 4;
            *(float4*)&Bs[k][c] = *(const float4*)(Bp + (long)k * bStride + c);
        }
    }
    {
        int r = t & 63;
        int kc = (t >> 6) * 32;
        if (r < cnt) {
            int grow = table ? sorted[start + r] : (start + r);
            const float4* src = (const float4*)(A + (long)grow * aStride + kc);
            #pragma unroll
            for (int i = 0; i < 8; i++) {
                float4 v = src[i];
                At[kc + 4*i + 0][r] = v.x;
                At[kc + 4*i + 1][r] = v.y;
                At[kc + 4*i + 2][r] = v.z;
                At[kc + 4*i + 3][r] = v.w;
            }
        } else {
            #pragma unroll
            for (int i = 0; i < 32; i++) At[kc + i][r] = 0.0f;
        }
    }
    __syncthreads();

    constexpr int CG   = BC / 4;
    constexpr int ROWS = BC / 16;
    const int c0 = (t % CG) * 4;
    const int r0 = (t / CG) * ROWS;
    float acc[ROWS][4] = {};
    #pragma unroll 8
    for (int k = 0; k < 128; k++) {
        float4 b = *(const float4*)&Bs[k][c0];
        float av[ROWS];
        #pragma unroll
        for (int i = 0; i < ROWS / 4; i++) {
            float4 a = *(const float4*)&At[k][r0 + 4 * i];
            av[4*i + 0] = a.x; av[4*i + 1] = a.y; av[4*i + 2] = a.z; av[4*i + 3] = a.w;
        }
        #pragma unroll
        for (int i = 0; i < ROWS; i++) {
            acc[i][0] += av[i] * b.x;
            acc[i][1] += av[i] * b.y;
            acc[i][2] += av[i] * b.z;
            acc[i][3] += av[i] * b.w;
        }
    }
    #pragma unroll
    for (int i = 0; i < ROWS; i++) {
        int r = r0 + i;
        if (r < cnt) {
            int grow = table ? sorted[start + r] : (start + r);
            float4 v = make_float4(acc[i][0] * alpha, acc[i][1] * alpha,
                                   acc[i][2] * alpha, acc[i][3] * alpha);
            *(float4*)&C[(long)gy * cChunkY + (long)grow * cStride + c0] = v;
        }
    }
}

// ---------------------------------------------------------------------------
// Fused h + skip kernel: stage gathered A-tile once, compute vs two B's.
//   h    = A @ Wup * aH        (dense rows via sorted)
//   skip = A @ Wsn[spec] * aSkip
// ---------------------------------------------------------------------------
__global__ __launch_bounds__(256) void k_hs(
    const float* __restrict__ A,        // node_feats (N,128)
    const float* __restrict__ Wup,      // (128,128)
    const float* __restrict__ Wsn,      // (128,10,128)
    float* __restrict__ h, float* __restrict__ skip,
    const int* __restrict__ sorted, const int4* __restrict__ table,
    const int* __restrict__ nTiles, float aH, float aSkip)
{
    __shared__ float At[128][64];
    __shared__ float Bs[128][64];
    const int t = threadIdx.x;
    const int gy = blockIdx.y;
    if (blockIdx.x >= nTiles[0]) return;
    int4 te = table[blockIdx.x];
    const int spec = te.x, start = te.y, cnt = te.z;

    { // gathered A tile (transposed)
        int r = t & 63, kc = (t >> 6) * 32;
        if (r < cnt) {
            int grow = sorted[start + r];
            const float4* src = (const float4*)(A + (long)grow * NFEAT + kc);
            #pragma unroll
            for (int i = 0; i < 8; i++) {
                float4 v = src[i];
                At[kc + 4*i + 0][r] = v.x;
                At[kc + 4*i + 1][r] = v.y;
                At[kc + 4*i + 2][r] = v.z;
                At[kc + 4*i + 3][r] = v.w;
            }
        } else {
            #pragma unroll
            for (int i = 0; i < 32; i++) At[kc + i][r] = 0.0f;
        }
    }
    const int c0 = (t & 15) * 4;       // 4 cols (of 64)
    const int r0 = (t >> 4) * 4;       // 4 rows
    #pragma unroll
    for (int pass = 0; pass < 2; pass++) {
        { // stage B tile: pass 0 = Wup (stride 128), pass 1 = Wsn[spec] (stride 1280)
            const float* Bp = pass == 0 ? (Wup + gy * 64)
                                        : (Wsn + spec * NFEAT + gy * 64);
            const int bStride = pass == 0 ? NFEAT : NFEAT * NSPEC;
            #pragma unroll
            for (int i = 0; i < 8; i++) {
                int idx = t + 256 * i;
                int k = idx >> 4;
                int c = (idx & 15) * 4;
                *(float4*)&Bs[k][c] = *(const float4*)(Bp + (long)k * bStride + c);
            }
        }
        __syncthreads();
        float acc[4][4] = {};
        #pragma unroll 8
        for (int k = 0; k < 128; k++) {
            float4 b = *(const float4*)&Bs[k][c0];
            float4 a = *(const float4*)&At[k][r0];
            float av[4] = {a.x, a.y, a.z, a.w};
            #pragma unroll
            for (int i = 0; i < 4; i++) {
                acc[i][0] += av[i] * b.x;
                acc[i][1] += av[i] * b.y;
                acc[i][2] += av[i] * b.z;
                acc[i][3] += av[i] * b.w;
            }
        }
        float* dst   = pass == 0 ? h : skip;
        float  alpha = pass == 0 ? aH : aSkip;
        #pragma unroll
        for (int i = 0; i < 4; i++) {
            int r = r0 + i;
            if (r < cnt) {
                int grow = sorted[start + r];
                float4 v = make_float4(acc[i][0] * alpha, acc[i][1] * alpha,
                                       acc[i][2] * alpha, acc[i][3] * alpha);
                *(float4*)&dst[(long)grow * NFEAT + gy * 64 + c0] = v;
            }
        }
        __syncthreads();   // all reads of Bs/At done before restage (and before exit)
    }
}

// ---------------------------------------------------------------------------
// Barrier-free per-wave edge kernel. Each WAVE owns a 16-edge tile end-to-end.
// Wave-lockstep => no __syncthreads after the one-time W1 staging.
// LDS/block: W1 2K + act 4x5K + ef 4x0.5K + meta ~0.75K ~= 25.3 KB.
// W2/W3/W4 read from global (L1/L2-resident). act rows padded to stride 20.
// w0: lane = 2 cols, 16 edges serial in-register -> 16-edge run-combined
// atomics (wave-uniform branches, whole-row 512B flushes).
// ---------------------------------------------------------------------------
#define ASTR 20   // act row stride in floats (16B-aligned, bank-spreading)

__global__ __launch_bounds__(256, 5) void k_edge(
    const int*   __restrict__ sendG,    // (E) receiver-sorted
    const int*   __restrict__ recvG,
    const float* __restrict__ sh0G,
    const float* __restrict__ efG,      // (E,8) receiver-sorted
    const float* __restrict__ W1,       // (8,64)   LDS
    const float* __restrict__ W2,       // (64,64)  via L1
    const float* __restrict__ W3,       // (64,64)  via L1
    const float* __restrict__ W4,       // (64,512) cols 0..127 via L1
    const float* __restrict__ h,        // (N,128) scaled
    float*       __restrict__ msgs0,    // (N,128) pre-zeroed
    int E)
{
    __shared__ float W1s[8][64];
    __shared__ float actS[4][64 * ASTR];
    __shared__ float efS[4][8 * 16];
    __shared__ int   sendS[4][16];
    __shared__ int   recvS[4][16];
    __shared__ float sh0S[4][16];

    const int t = threadIdx.x;
    if (t < 128) ((float4*)W1s)[t] = ((const float4*)W1)[t];
    __syncthreads();                       // only block-wide barrier

    const int wid = t >> 6, lane = t & 63;
    const int ntiles = (E + 15) >> 4;
    const int tile = blockIdx.x * 4 + wid;
    if (tile >= ntiles) return;
    const int base = tile << 4;

    float* act = actS[wid];
    float* ef  = efS[wid];

    // ---- stage meta (lanes 0-47) + edge feats transposed (all lanes) ----
    {
        int g = lane & 15, p = base + g;
        bool ok = p < E;
        if (lane < 16)      sendS[wid][g] = ok ? sendG[p] : 0;
        else if (lane < 32) recvS[wid][g] = ok ? recvG[p] : -1;
        else if (lane < 48) sh0S[wid][g]  = ok ? sh0G[p]  : 0.0f;
    }
    {
        int idx = lane * 2, e = idx >> 3, k = idx & 7;
        int p = base + e;
        float2 v = make_float2(0.f, 0.f);
        if (p < E) v = *(const float2*)(efG + (long)p * 8 + k);
        ef[k * 16 + e]       = v.x;
        ef[(k + 1) * 16 + e] = v.y;
    }
    // (intra-wave DS ordering: no barrier needed)

    const float s1 = 0.3535533905932738f;  // 1/sqrt(8)
    const float s2 = 0.125f;               // 1/sqrt(64)
    const int e4 = lane & 3;               // 4-edge chunk
    const int j4 = lane >> 2;              // 16 hidden quads

    // ---- t1: act = silu(ef @ W1 * s1), [64][16] k-major ----
    {
        float acc[4][4] = {};
        #pragma unroll
        for (int k = 0; k < 8; k++) {
            float4 a = *(const float4*)&ef[k * 16 + e4 * 4];
            float4 b = *(const float4*)&W1s[k][j4 * 4];
            float av[4] = {a.x, a.y, a.z, a.w};
            float bv[4] = {b.x, b.y, b.z, b.w};
            #pragma unroll
            for (int jj = 0; jj < 4; jj++)
                #pragma unroll
                for (int ee = 0; ee < 4; ee++)
                    acc[jj][ee] += av[ee] * bv[jj];
        }
        #pragma unroll
        for (int jj = 0; jj < 4; jj++) {
            float4 v; float x;
            x = acc[jj][0] * s1; v.x = x / (1.0f + __expf(-x));
            x = acc[jj][1] * s1; v.y = x / (1.0f + __expf(-x));
            x = acc[jj][2] * s1; v.z = x / (1.0f + __expf(-x));
            x = acc[jj][3] * s1; v.w = x / (1.0f + __expf(-x));
            *(float4*)&act[(j4 * 4 + jj) * ASTR + e4 * 4] = v;
        }
    }

    // ---- t2: in-place, W2 via L1 ----
    {
        float acc[4][4] = {};
        const float4* W2v = (const float4*)W2;
        #pragma unroll 4
        for (int k = 0; k < 64; k++) {
            float4 a = *(const float4*)&act[k * ASTR + e4 * 4];
            float4 b = W2v[k * 16 + j4];
            float av[4] = {a.x, a.y, a.z, a.w};
            float bv[4] = {b.x, b.y, b.z, b.w};
            #pragma unroll
            for (int jj = 0; jj < 4; jj++)
                #pragma unroll
                for (int ee = 0; ee < 4; ee++)
                    acc[jj][ee] += av[ee] * bv[jj];
        }
        #pragma unroll
        for (int jj = 0; jj < 4; jj++) {
            float4 v; float x;
            x = acc[jj][0] * s2; v.x = x / (1.0f + __expf(-x));
            x = acc[jj][1] * s2; v.y = x / (1.0f + __expf(-x));
            x = acc[jj][2] * s2; v.z = x / (1.0f + __expf(-x));
            x = acc[jj][3] * s2; v.w = x / (1.0f + __expf(-x));
            *(float4*)&act[(j4 * 4 + jj) * ASTR + e4 * 4] = v;
        }
    }

    // ---- t3: in-place, W3 via L1 ----
    {
        float acc[4][4] = {};
        const float4* W3v = (const float4*)W3;
        #pragma unroll 4
        for (int k = 0; k < 64; k++) {
            float4 a = *(const float4*)&act[k * ASTR + e4 * 4];
            float4 b = W3v[k * 16 + j4];
            float av[4] = {a.x, a.y, a.z, a.w};
            float bv[4] = {b.x, b.y, b.z, b.w};
            #pragma unroll
            for (int jj = 0; jj < 4; jj++)
                #pragma unroll
                for (int ee = 0; ee < 4; ee++)
                    acc[jj][ee] += av[ee] * bv[jj];
        }
        #pragma unroll
        for (int jj = 0; jj < 4; jj++) {
            float4 v; float x;
            x = acc[jj][0] * s2; v.x = x / (1.0f + __expf(-x));
            x = acc[jj][1] * s2; v.y = x / (1.0f + __expf(-x));
            x = acc[jj][2] * s2; v.z = x / (1.0f + __expf(-x));
            x = acc[jj][3] * s2; v.w = x / (1.0f + __expf(-x));
            *(float4*)&act[(j4 * 4 + jj) * ASTR + e4 * 4] = v;
        }
    }

    // ---- w0: lane owns 2 cols, all 16 edges in-register; k-outer ----
    {
        const int c0 = lane * 2;
        float wacc[16][2] = {};
        #pragma unroll 4
        for (int k = 0; k < 64; k++) {
            float2 w4 = *(const float2*)&W4[k * 512 + c0];
            float4 a0 = *(const float4*)&act[k * ASTR + 0];
            float4 a1 = *(const float4*)&act[k * ASTR + 4];
            float4 a2 = *(const float4*)&act[k * ASTR + 8];
            float4 a3 = *(const float4*)&act[k * ASTR + 12];
            float av[16] = {a0.x, a0.y, a0.z, a0.w, a1.x, a1.y, a1.z, a1.w,
                            a2.x, a2.y, a2.z, a2.w, a3.x, a3.y, a3.z, a3.w};
            #pragma unroll
            for (int e = 0; e < 16; e++) {
                wacc[e][0] += av[e] * w4.x;
                wacc[e][1] += av[e] * w4.y;
            }
        }
        // run-combined atomic scatter over 16 receiver-sorted edges
        int cur = recvS[wid][0];
        float sum0 = 0.f, sum1 = 0.f;
        #pragma unroll
        for (int e = 0; e < 16; e++) {
            int rcv = recvS[wid][e];          // wave-uniform
            if (rcv != cur) {
                if (cur >= 0) {
                    atomicAdd(&msgs0[(long)cur * NFEAT + c0],     sum0);
                    atomicAdd(&msgs0[(long)cur * NFEAT + c0 + 1], sum1);
                }
                cur = rcv; sum0 = 0.f; sum1 = 0.f;
            }
            float f = sh0S[wid][e] * s2;
            int snd = sendS[wid][e];
            float2 hv = *(const float2*)&h[(long)snd * NFEAT + c0];
            sum0 += wacc[e][0] * f * hv.x;
            sum1 += wacc[e][1] * f * hv.y;
        }
        if (cur >= 0) {
            atomicAdd(&msgs0[(long)cur * NFEAT + c0],     sum0);
            atomicAdd(&msgs0[(long)cur * NFEAT + c0 + 1], sum1);
        }
    }
}

// ---------------------------------------------------------------------------
extern "C" void kernel_launch(void* const* d_in, const int* in_sizes, int n_in,
                              void* d_out, int out_size, void* d_ws, size_t ws_size,
                              hipStream_t stream) {
    const float* node_feats = (const float*)d_in[1];
    const float* edge_attrs = (const float*)d_in[2];
    const float* edge_feats = (const float*)d_in[3];
    const int*   edge_index = (const int*)  d_in[4];
    const int*   species    = (const int*)  d_in[5];
    const float* Wsn        = (const float*)d_in[6];   // (128,10,128)
    const float* Wup        = (const float*)d_in[7];   // (128,128)
    const float* W1         = (const float*)d_in[8];   // (8,64)
    const float* W2         = (const float*)d_in[9];   // (64,64)
    const float* W3         = (const float*)d_in[10];  // (64,64)
    const float* W4         = (const float*)d_in[11];  // (64,512)
    const float* Wlin       = (const float*)d_in[12];  // (4,128,128) -> l=0
    const float* Wsm        = (const float*)d_in[13];  // (4,128,10,128) -> l=0
    const float* Wout       = (const float*)d_in[14];  // (128,128)

    const int N = in_sizes[5];
    const int E = in_sizes[4] / 2;
    const int NF = NFEAT;

    float* out     = (float*)d_out;
    float* message = out;               // (N,128)
    float* skip    = out + (long)N * NF;

    // workspace carve
    char* wsb = (char*)d_ws;
    size_t off = 0;
    auto carve = [&](size_t bytes) { void* p = wsb + off; off = (off + bytes + 255) & ~(size_t)255; return p; };
    float* h      = (float*)carve((size_t)N * NF * 4);
    float* msgs0  = (float*)carve((size_t)N * NF * 4);
    float* Tst    = (float*)carve((size_t)NSPEC * NF * NF * 4);
    float* Comb   = (float*)carve((size_t)NSPEC * NF * NF * 4);
    int*   sorted = (int*)carve((size_t)N * 4);
    int*   counts = (int*)carve(64);
    int*   cursor = (int*)carve(64);
    int*   nTiles = (int*)carve(16);
    int4*  table  = (int4*)carve(256 * 16);
    int*   ehist  = (int*)carve((size_t)N * 4);
    int*   ecursor= (int*)carve((size_t)N * 4);
    int*   sendG  = (int*)carve((size_t)E * 4);
    int*   recvG  = (int*)carve((size_t)E * 4);
    float* sh0G   = (float*)carve((size_t)E * 4);
    float* efG    = (float*)carve((size_t)E * 8 * 4);

    const float aH    = 1.0f / sqrtf((float)NF);
    const float aSkip = 1.0f / sqrtf((float)(NF * NSPEC));
    const float cTot  = 0.25f / ((float)NF * sqrtf((float)(NF * NSPEC)));

    hipMemsetAsync(counts, 0, 64, stream);
    hipMemsetAsync(ehist, 0, (size_t)N * 4, stream);
    hipMemsetAsync(msgs0, 0, (size_t)N * NF * 4, stream);

    // histograms, species table, node sort, edge scan + payload gather
    k_histboth<<<(max(N, E) + 255) / 256, 256, 0, stream>>>(species, edge_index, counts, ehist, N, E);
    k_build  <<<1, 256, 0, stream>>>(counts, cursor, table, nTiles);
    k_scatter<<<(N + 255) / 256, 256, 0, stream>>>(species, cursor, sorted, N);
    k_escan  <<<1, 256, 0, stream>>>(ehist, ecursor, N);
    k_egather<<<(E + 255) / 256, 256, 0, stream>>>(edge_index, edge_attrs, edge_feats,
                                                   ecursor, sendG, recvG, sh0G, efG, E);

    const int mTiles   = (N + 63) / 64;
    const int maxTiles = mTiles + NSPEC;

    // fused h + skip (one gathered A-tile, two B passes)
    k_hs<<<dim3(maxTiles, 2), 256, 0, stream>>>(
        node_feats, Wup, Wsn, h, skip, sorted, table, nTiles, aH, aSkip);

    // Tst[s] = W_lin0 @ Wsm0[:,s,:]             (BC=128, gy=species)
    k_gemm<128><<<dim3(2, NSPEC), 256, 0, stream>>>(
        Wlin, NF, Wsm, NF * NSPEC, 0, Tst, NF, NF * NF, NF, 1.0f, nullptr, nullptr, nullptr);

    // Comb = Tst(1280x128) @ W_out * cTot       (BC=128)
    k_gemm<128><<<dim3((NSPEC * NF) / 64, 1), 256, 0, stream>>>(
        Tst, NF, Wout, NF, 0, Comb, NF, NF, NSPEC * NF, cTot, nullptr, nullptr, nullptr);

    // barrier-free per-wave edge MLP + run-combined atomics
    int eTiles = (E + 15) / 16;
    int eBlocks = (eTiles + 3) / 4;
    k_edge<<<eBlocks, 256, 0, stream>>>(
        sendG, recvG, sh0G, efG, W1, W2, W3, W4, h, msgs0, E);

    // message = gatherGEMM(msgs0, Comb[s])      (BC=64)
    k_gemm<64><<<dim3(maxTiles, 2), 256, 0, stream>>>(
        msgs0, NF, Comb, NF, NF * NF, message, NF, 64, N, 1.0f, sorted, table, nTiles);
}